// Round 8
// baseline (680.199 us; speedup 1.0000x reference)
//
#include <hip/hip_runtime.h>
#include <hip/hip_bf16.h>

typedef __hip_bfloat16 bf16;
typedef unsigned short u16;
typedef unsigned int   u32;

#define B_   2
#define CIN_ 64
#define C_   128
#define H_   64
#define W_   1024
#define HW_  (H_*W_)
#define H2_  32
#define W2_  512
#define HW2_ (H2_*W2_)

typedef __attribute__((ext_vector_type(8))) short bf16x8;
typedef __attribute__((ext_vector_type(4))) float f32x4;

// Transformed bf16 weights (row-major, k-contiguous per co row).
#define OFF_C2  0
#define OFF_C3  73728
#define OFF_C4  221184
#define OFF_C5  286720
#define OFF_C1  335872
#define OFF_PW  344064
#define OFF_LIN 393216
#define WTS_TOT 655360
__device__ __align__(16) u16 g_wts[WTS_TOT];
// Module-owned activation buffers (both batches live).
// b1/b2/b3 hold conv-pipeline activations in PX-MAJOR [hw][128] bf16 layout.
// (b1 later reused for h in [c][hw]; b2 later reused for wn.)
__device__ __align__(16) u16 g_b1[(size_t)B_*C_*HW_];      // 32 MiB
__device__ __align__(16) u16 g_b2[(size_t)B_*C_*HW_];      // 32 MiB
__device__ __align__(16) u16 g_b3[(size_t)B_*C_*HW_];      // 32 MiB
__device__ __align__(16) u16 g_xb[(size_t)B_*HW_*CIN_];    // 16 MiB (xb [hw][64])

__device__ __forceinline__ float bits2f(u16 u){
    u32 x = ((u32)u) << 16; float f; __builtin_memcpy(&f, &x, 4); return f;
}
__device__ __forceinline__ u16 f2bits(float v){
    bf16 h = __float2bfloat16(v); u16 u; __builtin_memcpy(&u, &h, 2); return u;
}
__device__ __forceinline__ float lrelu(float v){ return v > 0.f ? v : 0.01f*v; }
__device__ __forceinline__ float relu (float v){ return v > 0.f ? v : 0.f; }

// ---------------------------------------------------------------------------
// MFMA tile machinery. Tile M=128 (co) x N=128 (pix), K-step 32.
// B tiles live in LDS at row stride PSTR (full-K rows, 16B-aligned).
// A fragments are read straight from global (weights are L2-resident) —
// proven pattern from k_yfused (R7).
// ---------------------------------------------------------------------------
#define PSTR 136   // full-K (128) B row stride
#define TSTR 136   // epilogue transpose tile stride (16B-aligned rows)

// One K=32 MFMA step: A from global weights (row stride wstr, col offset aoff),
// B from LDS (row stride bstr, col offset boff).
__device__ __forceinline__ void mfma_k32(const u16* __restrict__ wA, int wstr, int aoff,
                                         const u16* Bs, int bstr, int boff,
                                         int lane, int wm, int wn_, f32x4 acc[4][4])
{
    const int quad = lane >> 4, l15 = lane & 15;
    bf16x8 a[4], b[4];
#pragma unroll
    for (int i = 0; i < 4; i++)
        a[i] = *(const bf16x8*)&wA[(size_t)(wm*64 + i*16 + l15)*wstr + aoff + quad*8];
#pragma unroll
    for (int j = 0; j < 4; j++)
        b[j] = *(const bf16x8*)&Bs[(wn_*64 + j*16 + l15)*bstr + boff + quad*8];
#pragma unroll
    for (int i = 0; i < 4; i++)
#pragma unroll
        for (int j = 0; j < 4; j++)
            acc[i][j] = __builtin_amdgcn_mfma_f32_16x16x32_bf16(a[i], b[j], acc[i][j], 0, 0, 0);
}

__device__ __forceinline__ void init_bias(f32x4 acc[4][4], const float* bias, int wm, int lane)
{
    const int quad = lane >> 4;
#pragma unroll
    for (int i = 0; i < 4; i++)
#pragma unroll
        for (int r = 0; r < 4; r++) {
            float bv = bias[wm*64 + i*16 + quad*4 + r];
#pragma unroll
            for (int j = 0; j < 4; j++) acc[i][j][r] = bv;
        }
}

// ---------------------------------------------------------------------------
// x transpose: fp32 [64][HW] -> bf16 [HW][64] (enables vector B-staging in
// c2 conv and resA shortcut). grid (512, B_), block 256.
// ---------------------------------------------------------------------------
#define XTS 70
__global__ __launch_bounds__(256)
void k_xtrans(const float* __restrict__ x0, u16* __restrict__ xb0)
{
    __shared__ __align__(16) u16 T[128*XTS];
    const int tid = threadIdx.x;
    const float* x = x0 + (size_t)blockIdx.y*CIN_*HW_;
    u16* xb = xb0 + (size_t)blockIdx.y*HW_*CIN_;
    const int pix0 = blockIdx.x * 128;
#pragma unroll
    for (int r = 0; r < 8; r++) {
        int e = tid + 256*r;               // 2048 items: 64 c x 32 px-groups
        int c = e >> 5, p4 = (e & 31)*4;
        float4 v = *(const float4*)&x[(size_t)c*HW_ + pix0 + p4];
        T[(p4+0)*XTS + c] = f2bits(v.x);
        T[(p4+1)*XTS + c] = f2bits(v.y);
        T[(p4+2)*XTS + c] = f2bits(v.z);
        T[(p4+3)*XTS + c] = f2bits(v.w);
    }
    __syncthreads();
#pragma unroll
    for (int r = 0; r < 4; r++) {
        int e = tid + 256*r;               // 1024 granules: 128 px x 8
        int p = e >> 3, g = e & 7;
        // rows are XTS*2=140B apart; granule addr 8B-aligned -> copy as 2 uint2
        const u16* s = &T[p*XTS + g*8];
        u16* d = &xb[(size_t)(pix0+p)*CIN_ + g*8];
        *(uint2*)&d[0] = *(const uint2*)&s[0];
        *(uint2*)&d[4] = *(const uint2*)&s[4];
    }
}

// ---------------------------------------------------------------------------
// Conv as shift-decomposed GEMM over px-major activations (full-K staging).
// grid (512, B_), block 256.  in: [hw][CI] bf16, out: [hw][128] bf16.
// Per tap: 2 barriers, full B-tile [128px][CI] staged once, CI/32 MFMA K-steps
// with A-fragments straight from global weights.
// ---------------------------------------------------------------------------
template<int CI, int KS, int DIL, int PAD>
__global__ __launch_bounds__(256)
void k_conv(const u16* __restrict__ in0, const u16* __restrict__ wT,
            const float* __restrict__ bias, const float* __restrict__ bns,
            const float* __restrict__ bnb, u16* __restrict__ out0)
{
    __shared__ __align__(16) u16 Bs[128*PSTR];    // 34.8 KB; reused as T in epilogue
    const int tid = threadIdx.x, lane = tid & 63, wave = tid >> 6;
    const int wm = wave & 1, wn_ = wave >> 1;
    const u16* in = in0 + (size_t)blockIdx.y*HW_*CI;
    u16* out = out0 + (size_t)blockIdx.y*HW_*C_;
    const int pix0 = blockIdx.x * 128;
    const int y = pix0 >> 10, x0 = pix0 & 1023;

    f32x4 acc[4][4];
    init_bias(acc, bias, wm, lane);

    for (int p = 0; p < KS*KS; p++) {
        int dy = (p/KS)*DIL - PAD, dx = (p%KS)*DIL - PAD;
        int yy = y + dy;
        if (yy < 0 || yy >= H_) continue;          // block-uniform (tile = one row)
        const u16* srow = in + (size_t)yy*W_*CI;
        const u16* wp = wT + p*128*CI;
        __syncthreads();                           // prev tap's MFMA done with Bs
        if (CI == 128) {
#pragma unroll
            for (int r = 0; r < 8; r++) {
                int e = tid + 256*r;
                int px = e >> 4, g = e & 15;
                int xx = x0 + dx + px;
                uint4 v = make_uint4(0u, 0u, 0u, 0u);
                if ((unsigned)xx < (unsigned)W_)
                    v = *(const uint4*)&srow[(size_t)xx*CI + g*8];
                *(uint4*)&Bs[px*PSTR + g*8] = v;
            }
        } else {                                   // CI == 64
#pragma unroll
            for (int r = 0; r < 4; r++) {
                int e = tid + 256*r;
                int px = e >> 3, g = e & 7;
                int xx = x0 + dx + px;
                uint4 v = make_uint4(0u, 0u, 0u, 0u);
                if ((unsigned)xx < (unsigned)W_)
                    v = *(const uint4*)&srow[(size_t)xx*CI + g*8];
                *(uint4*)&Bs[px*PSTR + g*8] = v;
            }
        }
        __syncthreads();                           // Bs ready
#pragma unroll
        for (int kc = 0; kc < CI/32; kc++)
            mfma_k32(wp, CI, kc*32, Bs, PSTR, kc*32, lane, wm, wn_, acc);
    }
    // Epilogue: bn+lrelu -> LDS transpose tile [px][co] -> vector px-major store
    const int quad = lane >> 4, l15 = lane & 15;
    u16* T = Bs;
    __syncthreads();                               // all waves done reading Bs
#pragma unroll
    for (int i = 0; i < 4; i++)
#pragma unroll
        for (int r = 0; r < 4; r++) {
            int co = wm*64 + i*16 + quad*4 + r;
            float ss = bns[co], tt = bnb[co];
#pragma unroll
            for (int j = 0; j < 4; j++) {
                float v = lrelu(acc[i][j][r]) * ss + tt;
                T[(wn_*64 + j*16 + l15)*TSTR + co] = f2bits(v);
            }
        }
    __syncthreads();
#pragma unroll
    for (int r = 0; r < 8; r++) {
        int e = tid + 256*r;
        int px = e >> 4, g = e & 15;
        *(uint4*)&out[(size_t)(pix0+px)*C_ + g*8] = *(const uint4*)&T[px*TSTR + g*8];
    }
}

// ---------------------------------------------------------------------------
// resA = bn3(lrelu(c5_w@[A1;A2;A3] + c5_b)) + lrelu(c1_w@x + c1_b)  (fp32 out)
// Inputs xb/A1/A2/A3 px-major; full-K staging; A-frags from global weights.
// ---------------------------------------------------------------------------
__global__ __launch_bounds__(256)
void k_resA(const u16* __restrict__ xb0, const u16* __restrict__ a10,
            const u16* __restrict__ a20, const u16* __restrict__ a30,
            const u16* __restrict__ wc1, const float* __restrict__ c1b,
            const u16* __restrict__ wc5, const float* __restrict__ c5b,
            const float* __restrict__ s3, const float* __restrict__ b3,
            float* __restrict__ out0)
{
    __shared__ __align__(16) u16 Bs[128*PSTR];    // 34.8 KB
    const int tid = threadIdx.x, lane = tid & 63, wave = tid >> 6;
    const int wm = wave & 1, wn_ = wave >> 1;
    const int b = blockIdx.y;
    const u16* xb = xb0 + (size_t)b*HW_*CIN_;
    const u16* aa[3] = { a10 + (size_t)b*HW_*C_, a20 + (size_t)b*HW_*C_, a30 + (size_t)b*HW_*C_ };
    float* out = out0 + (size_t)b*C_*HW_;
    const int pix0 = blockIdx.x * 128;
    const int quad = lane >> 4, l15 = lane & 15;

    // shortcut: K=64 over xb (full-K staged once)
    f32x4 acc[4][4];
    init_bias(acc, c1b, wm, lane);
#pragma unroll
    for (int r = 0; r < 4; r++) {
        int e = tid + 256*r;
        int px = e >> 3, g = e & 7;
        *(uint4*)&Bs[px*PSTR + g*8] = *(const uint4*)&xb[(size_t)(pix0+px)*CIN_ + g*8];
    }
    __syncthreads();
#pragma unroll
    for (int kc = 0; kc < 2; kc++)
        mfma_k32(wc1, 64, kc*32, Bs, PSTR, kc*32, lane, wm, wn_, acc);

    float sc[4][4][4];
#pragma unroll
    for (int i = 0; i < 4; i++)
#pragma unroll
        for (int j = 0; j < 4; j++)
#pragma unroll
            for (int r = 0; r < 4; r++) sc[i][j][r] = lrelu(acc[i][j][r]);

    // main: K=384 over [A1;A2;A3], one full-K=128 stage per source
    init_bias(acc, c5b, wm, lane);
    for (int s = 0; s < 3; s++) {
        const u16* src = aa[s] + (size_t)pix0*C_;
        __syncthreads();                           // prev MFMA done with Bs
#pragma unroll
        for (int r = 0; r < 8; r++) {
            int e = tid + 256*r;
            int px = e >> 4, g = e & 15;
            *(uint4*)&Bs[px*PSTR + g*8] = *(const uint4*)&src[(size_t)px*C_ + g*8];
        }
        __syncthreads();
#pragma unroll
        for (int kc = 0; kc < 4; kc++)
            mfma_k32(wc5, 384, s*128 + kc*32, Bs, PSTR, kc*32, lane, wm, wn_, acc);
    }
#pragma unroll
    for (int i = 0; i < 4; i++)
#pragma unroll
        for (int r = 0; r < 4; r++) {
            int co = wm*64 + i*16 + quad*4 + r;
            float ss = s3[co], tt = b3[co];
#pragma unroll
            for (int j = 0; j < 4; j++) {
                float v = lrelu(acc[i][j][r]) * ss + tt + sc[i][j][r];
                out[co*HW_ + pix0 + wn_*64 + j*16 + l15] = v;
            }
        }
}

// ---------------------------------------------------------------------------
// Fused 3-layer pointwise MLP: h = relu(bn(W3 relu(bn(W2 relu(bn(W1 resA)))))).
// One block owns 128 pixels end-to-end; inter-layer activations in LDS.
// A-frags from global pw weights (no As tile); 3 barriers total.
// ---------------------------------------------------------------------------
__global__ __launch_bounds__(256)
void k_pw3(const float* __restrict__ in0, const u16* __restrict__ w,
           const float* __restrict__ pb, const float* __restrict__ ps,
           const float* __restrict__ pbb, u16* __restrict__ out0)
{
    __shared__ __align__(16) u16 B0[128*PSTR];
    __shared__ __align__(16) u16 B1[128*PSTR];
    const int tid = threadIdx.x, lane = tid & 63, wave = tid >> 6;
    const int wm = wave & 1, wn_ = wave >> 1;
    const int b = blockIdx.y;
    const float* in = in0 + (size_t)b*C_*HW_;
    u16* out = out0 + (size_t)b*C_*HW_;
    const int pix0 = blockIdx.x * 128;
    const int quad = lane >> 4, l15 = lane & 15;

    // Stage B0 [pix][k] from fp32 resA (vector loads along pix, scatter to LDS)
    for (int e = tid; e < 128*32; e += 256) {
        int kk = e >> 5, j4 = (e & 31)*4;
        float4 v = *(const float4*)&in[kk*HW_ + pix0 + j4];
        u16* d = &B0[j4*PSTR + kk];
        d[0]      = f2bits(v.x);
        d[PSTR]   = f2bits(v.y);
        d[2*PSTR] = f2bits(v.z);
        d[3*PSTR] = f2bits(v.w);
    }

    u16* Bc = B0;
    u16* Bn = B1;
#pragma unroll
    for (int L = 0; L < 3; L++) {
        f32x4 acc[4][4];
        init_bias(acc, pb + L*128, wm, lane);
        __syncthreads();                           // Bc writes visible
#pragma unroll
        for (int kc = 0; kc < 4; kc++)
            mfma_k32(w + L*16384, 128, kc*32, Bc, PSTR, kc*32, lane, wm, wn_, acc);
        const float* ss = ps + L*128;
        const float* tt = pbb + L*128;
        if (L < 2) {
#pragma unroll
            for (int i = 0; i < 4; i++)
#pragma unroll
                for (int r = 0; r < 4; r++) {
                    int co = wm*64 + i*16 + quad*4 + r;
                    float s1 = ss[co], t1 = tt[co];
#pragma unroll
                    for (int j = 0; j < 4; j++) {
                        float v = relu(acc[i][j][r] * s1 + t1);
                        Bn[(wn_*64 + j*16 + l15)*PSTR + co] = f2bits(v);
                    }
                }
            u16* t = Bc; Bc = Bn; Bn = t;
        } else {
#pragma unroll
            for (int i = 0; i < 4; i++)
#pragma unroll
                for (int r = 0; r < 4; r++) {
                    int co = wm*64 + i*16 + quad*4 + r;
                    float s1 = ss[co], t1 = tt[co];
#pragma unroll
                    for (int j = 0; j < 4; j++) {
                        float v = relu(acc[i][j][r] * s1 + t1);
                        out[co*HW_ + pix0 + wn_*64 + j*16 + l15] = f2bits(v);
                    }
                }
        }
    }
}

// ---------------------------------------------------------------------------
// WeightNet: xyz fp32 -> bf16 [16,25,H2,W2] per batch.
// ---------------------------------------------------------------------------
__global__ __launch_bounds__(256)
void wn_kernel(const float* __restrict__ xyz0,
               const float* __restrict__ w1w, const float* __restrict__ w1b,
               const float* __restrict__ w2w, const float* __restrict__ w2b,
               const float* __restrict__ w3w, const float* __restrict__ w3b,
               const float* __restrict__ s1, const float* __restrict__ bb1,
               const float* __restrict__ s2, const float* __restrict__ bb2,
               const float* __restrict__ s3, const float* __restrict__ bb3,
               u16* __restrict__ out0)
{
    const float* xyz = xyz0 + (size_t)blockIdx.y*3*HW_;
    u16* out = out0 + (size_t)blockIdx.y*400*HW2_;
    int idx = blockIdx.x*256 + threadIdx.x;
    int j = idx & (W2_-1); int t = idx >> 9;
    int i = t & (H2_-1);   int k = t >> 5;
    int kh = k / 5, kw = k - kh*5;
    int yy = 2*i + kh - 2, xx = 2*j + kw - 2;
    bool inr = (yy >= 0 && yy < H_ && xx >= 0 && xx < W_);

    float g[3];
#pragma unroll
    for (int c = 0; c < 3; c++) {
        float ctr = xyz[c*HW_ + (2*i)*W_ + 2*j];
        float v = inr ? xyz[c*HW_ + yy*W_ + xx] : 0.f;
        g[c] = v - ctr;
    }
    float a1[8];
#pragma unroll
    for (int n = 0; n < 8; n++) {
        float v = w1b[n];
#pragma unroll
        for (int c = 0; c < 3; c++) v += w1w[n*3 + c] * g[c];
        a1[n] = relu(v * s1[n] + bb1[n]);
    }
    float a2[8];
#pragma unroll
    for (int n = 0; n < 8; n++) {
        float v = w2b[n];
#pragma unroll
        for (int m = 0; m < 8; m++) v += w2w[n*8 + m] * a1[m];
        a2[n] = relu(v * s2[n] + bb2[n]);
    }
#pragma unroll
    for (int n = 0; n < 16; n++) {
        float v = w3b[n];
#pragma unroll
        for (int m = 0; m < 8; m++) v += w3w[n*8 + m] * a2[m];
        v = relu(v * s3[n] + bb3[n]);
        out[(n*25 + k)*HW2_ + i*W2_ + j] = f2bits(v);
    }
}

// ---------------------------------------------------------------------------
// Fused ycompute + linear head (R7-proven; unchanged):
//   y[px][c*16+n] = sum_k unf(h)[c][k][px] * wn[n][k][px]     (bf16, LDS only)
//   resB[co][px]  = relu(bn(lin_w @ y + lin_b))               (fp32 out)
// ---------------------------------------------------------------------------
__global__ __launch_bounds__(512)
void k_yfused(const u16* __restrict__ h0, const u16* __restrict__ wn0,
              const u16* __restrict__ w, const float* __restrict__ bias,
              const float* __restrict__ bns, const float* __restrict__ bnb,
              float* __restrict__ out0)
{
    __shared__ __align__(16) float slab[40*148];   // 23.7 KB (8 cc * 5 rr rows)
    __shared__ __align__(16) u16 Bs[64*PSTR];      // 17.4 KB (y sub-tile)
    const int tid = threadIdx.x;
    const int bx = blockIdx.x;
    const int j0 = (bx & 7) * 64;
    const int i2 = bx >> 3;
    const int b  = blockIdx.y;
    const u16* h  = h0  + (size_t)b*C_*HW_;
    const u16* wn = wn0 + (size_t)b*400*HW2_;
    float* out = out0 + (size_t)b*C_*HW2_;

    // phase-1 roles: n fast (16-way broadcast group), pxq = px-pair index
    const int n = tid & 15, pxq = tid >> 4;        // pxq 0..31
    // phase-2 roles
    const int lane = tid & 63, wave = tid >> 6;
    const int wm4 = wave & 3, wnp = wave >> 2;     // 4x32 co, 2x32 px
    const int quad = lane >> 4, l15 = lane & 15;

    // wn for this thread's (n, px-pair): 25 taps f32 in regs (50 VGPR)
    float wnreg[25][2];
    {
        const u16* wb = wn + (n*25)*HW2_ + i2*W2_ + j0 + pxq*2;
#pragma unroll
        for (int k = 0; k < 25; k++) {
            u32 t = *(const u32*)(wb + k*HW2_);
            wnreg[k][0] = bits2f((u16)(t & 0xffff));
            wnreg[k][1] = bits2f((u16)(t >> 16));
        }
    }

    // A-fragment lane base offsets into lin_w [128][2048]
    const int bA0 = (wm4*32 +  0 + l15)*2048 + quad*8;
    const int bA1 = (wm4*32 + 16 + l15)*2048 + quad*8;

    f32x4 acc[2][2];
#pragma unroll
    for (int i = 0; i < 2; i++)
#pragma unroll
        for (int r = 0; r < 4; r++) {
            float bv = bias[wm4*32 + i*16 + quad*4 + r];
            acc[i][0][r] = bv;
            acc[i][1][r] = bv;
        }

    for (int c0 = 0; c0 < 128; c0 += 8) {
        __syncthreads();                           // prev MFMA done with Bs; slab free
        // Fill slab: 8 cc x 5 rr x 18 uint4-groups
        for (int e = tid; e < 720; e += 512) {
            int cc = e / 90, rem = e - cc*90;
            int rr = rem / 18, g = rem - rr*18;
            int yy = 2*i2 + rr - 2;
            int xs0 = 2*j0 - 8 + 8*g;              // 16B-aligned global offset
            float f[8];
            if ((unsigned)yy < (unsigned)H_ && (unsigned)xs0 <= (unsigned)(W_-8)) {
                uint4 v = *(const uint4*)&h[(c0+cc)*HW_ + yy*W_ + xs0];
                f[0] = bits2f((u16)(v.x & 0xffff)); f[1] = bits2f((u16)(v.x >> 16));
                f[2] = bits2f((u16)(v.y & 0xffff)); f[3] = bits2f((u16)(v.y >> 16));
                f[4] = bits2f((u16)(v.z & 0xffff)); f[5] = bits2f((u16)(v.z >> 16));
                f[6] = bits2f((u16)(v.w & 0xffff)); f[7] = bits2f((u16)(v.w >> 16));
            } else if ((unsigned)yy < (unsigned)H_) {
#pragma unroll
                for (int m = 0; m < 8; m++) {
                    int xs = xs0 + m;
                    f[m] = ((unsigned)xs < (unsigned)W_)
                         ? bits2f(h[(c0+cc)*HW_ + yy*W_ + xs]) : 0.f;
                }
            } else {
#pragma unroll
                for (int m = 0; m < 8; m++) f[m] = 0.f;
            }
            float* d = &slab[(cc*5 + rr)*148 + 2 + 8*g];
            *(float2*)(d+0) = make_float2(f[0], f[1]);
            *(float2*)(d+2) = make_float2(f[2], f[3]);
            *(float2*)(d+4) = make_float2(f[4], f[5]);
            *(float2*)(d+6) = make_float2(f[6], f[7]);
        }
        // Issue this chunk's A-fragments (global->reg; L2-resident lin_w)
        bf16x8 af0[4], af1[4];
#pragma unroll
        for (int kc = 0; kc < 4; kc++) {
            af0[kc] = *(const bf16x8*)&w[bA0 + c0*16 + kc*32];
            af1[kc] = *(const bf16x8*)&w[bA1 + c0*16 + kc*32];
        }
        __syncthreads();                           // slab ready
        // y-compute into Bs [px][cc*16+n]
#pragma unroll 2
        for (int cc = 0; cc < 8; cc++) {
            float yv0 = 0.f, yv1 = 0.f;
#pragma unroll
            for (int rr = 0; rr < 5; rr++) {
                const float* fr = &slab[(cc*5 + rr)*148 + 8 + 4*pxq];
                float4 A  = *(const float4*)fr;
                float4 Bv = *(const float4*)(fr + 4);
                yv0 += A.x*wnreg[rr*5+0][0] + A.y*wnreg[rr*5+1][0]
                     + A.z*wnreg[rr*5+2][0] + A.w*wnreg[rr*5+3][0]
                     + Bv.x*wnreg[rr*5+4][0];
                yv1 += A.z*wnreg[rr*5+0][1] + A.w*wnreg[rr*5+1][1]
                     + Bv.x*wnreg[rr*5+2][1] + Bv.y*wnreg[rr*5+3][1]
                     + Bv.z*wnreg[rr*5+4][1];
            }
            Bs[(2*pxq)  *PSTR + cc*16 + n] = f2bits(yv0);
            Bs[(2*pxq+1)*PSTR + cc*16 + n] = f2bits(yv1);
        }
        __syncthreads();                           // Bs ready
        // MFMA: A from regs, B from Bs
#pragma unroll
        for (int kc = 0; kc < 4; kc++) {
            bf16x8 b0 = *(const bf16x8*)&Bs[(wnp*32 +  0 + l15)*PSTR + kc*32 + quad*8];
            bf16x8 b1 = *(const bf16x8*)&Bs[(wnp*32 + 16 + l15)*PSTR + kc*32 + quad*8];
            acc[0][0] = __builtin_amdgcn_mfma_f32_16x16x32_bf16(af0[kc], b0, acc[0][0], 0, 0, 0);
            acc[0][1] = __builtin_amdgcn_mfma_f32_16x16x32_bf16(af0[kc], b1, acc[0][1], 0, 0, 0);
            acc[1][0] = __builtin_amdgcn_mfma_f32_16x16x32_bf16(af1[kc], b0, acc[1][0], 0, 0, 0);
            acc[1][1] = __builtin_amdgcn_mfma_f32_16x16x32_bf16(af1[kc], b1, acc[1][1], 0, 0, 0);
        }
    }
    // epilogue: bn + relu -> fp32 resB
#pragma unroll
    for (int i = 0; i < 2; i++)
#pragma unroll
        for (int r = 0; r < 4; r++) {
            int co = wm4*32 + i*16 + quad*4 + r;
            float ss = bns[co], tt = bnb[co];
#pragma unroll
            for (int j = 0; j < 2; j++) {
                float v = relu(acc[i][j][r] * ss + tt);
                out[co*HW2_ + i2*W2_ + j0 + wnp*32 + j*16 + l15] = v;
            }
        }
}

// ---------------------------------------------------------------------------
// Weight transform: fp32 -> bf16 g_wts (k-contiguous layouts).
// ---------------------------------------------------------------------------
__global__ __launch_bounds__(256)
void k_wtrans(const float* __restrict__ c2w, const float* __restrict__ c3w,
              const float* __restrict__ c4w, const float* __restrict__ c5w,
              const float* __restrict__ c1w, const float* __restrict__ pw,
              const float* __restrict__ linw)
{
    int i = blockIdx.x*256 + threadIdx.x;
    if (i >= WTS_TOT) return;
    float v;
    if (i < OFF_C3) {
        int p = i / 8192, rem = i - p*8192;
        int co = rem >> 6, ci = rem & 63;
        v = c2w[(co*64 + ci)*9 + p];
    } else if (i < OFF_C4) {
        int t = i - OFF_C3;
        int p = t / 16384, rem = t - p*16384;
        int co = rem >> 7, ci = rem & 127;
        v = c3w[(co*128 + ci)*9 + p];
    } else if (i < OFF_C5) {
        int t = i - OFF_C4;
        int p = t / 16384, rem = t - p*16384;
        int co = rem >> 7, ci = rem & 127;
        v = c4w[(co*128 + ci)*4 + p];
    } else if (i < OFF_C1)  v = c5w[i - OFF_C5];
    else if (i < OFF_PW)    v = c1w[i - OFF_C1];
    else if (i < OFF_LIN)   v = pw[i - OFF_PW];
    else                    v = linw[i - OFF_LIN];
    g_wts[i] = f2bits(v);
}

// ---------------------------------------------------------------------------
extern "C" void kernel_launch(void* const* d_in, const int* in_sizes, int n_in,
                              void* d_out, int out_size, void* d_ws, size_t ws_size,
                              hipStream_t stream)
{
    const float* x     = (const float*)d_in[0];
    const float* xyz   = (const float*)d_in[1];
    const float* c1_w  = (const float*)d_in[2];
    const float* c1_b  = (const float*)d_in[3];
    const float* c2_w  = (const float*)d_in[4];
    const float* c2_b  = (const float*)d_in[5];
    const float* c3_w  = (const float*)d_in[6];
    const float* c3_b  = (const float*)d_in[7];
    const float* c4_w  = (const float*)d_in[8];
    const float* c4_b  = (const float*)d_in[9];
    const float* c5_w  = (const float*)d_in[10];
    const float* c5_b  = (const float*)d_in[11];
    const float* rbn_s = (const float*)d_in[12];
    const float* rbn_b = (const float*)d_in[13];
    const float* p_w   = (const float*)d_in[14];
    const float* p_b   = (const float*)d_in[15];
    const float* pbn_s = (const float*)d_in[16];
    const float* pbn_b = (const float*)d_in[17];
    const float* lin_w = (const float*)d_in[18];
    const float* lin_b = (const float*)d_in[19];
    const float* w1_w  = (const float*)d_in[20];
    const float* w1_b  = (const float*)d_in[21];
    const float* w2_w  = (const float*)d_in[22];
    const float* w2_b  = (const float*)d_in[23];
    const float* w3_w  = (const float*)d_in[24];
    const float* w3_b  = (const float*)d_in[25];
    const float* wbn1_s = (const float*)d_in[26];
    const float* wbn1_b = (const float*)d_in[27];
    const float* wbn2_s = (const float*)d_in[28];
    const float* wbn2_b = (const float*)d_in[29];
    const float* wbn3_s = (const float*)d_in[30];
    const float* wbn3_b = (const float*)d_in[31];

    float* outB = (float*)d_out;                     // [2,128,32,512] fp32
    float* outA = outB + (size_t)B_*C_*HW2_;         // [2,128,64,1024] fp32

    u16 *wts, *b1, *b2, *b3, *xb;
    { void* p; hipGetSymbolAddress(&p, HIP_SYMBOL(g_wts)); wts = (u16*)p; }
    { void* p; hipGetSymbolAddress(&p, HIP_SYMBOL(g_b1));  b1  = (u16*)p; }
    { void* p; hipGetSymbolAddress(&p, HIP_SYMBOL(g_b2));  b2  = (u16*)p; }
    { void* p; hipGetSymbolAddress(&p, HIP_SYMBOL(g_b3));  b3  = (u16*)p; }
    { void* p; hipGetSymbolAddress(&p, HIP_SYMBOL(g_xb));  xb  = (u16*)p; }

    dim3 blk(256);

    k_wtrans<<<dim3((WTS_TOT + 255)/256), blk, 0, stream>>>(c2_w, c3_w, c4_w, c5_w,
                                                            c1_w, p_w, lin_w);
    k_xtrans<<<dim3(512, B_), blk, 0, stream>>>(x, xb);
    k_conv<64,3,1,1><<<dim3(512, B_), blk, 0, stream>>>(xb, wts+OFF_C2, c2_b,
                                                        rbn_s, rbn_b, b1);
    k_conv<128,3,2,2><<<dim3(512, B_), blk, 0, stream>>>(b1, wts+OFF_C3, c3_b,
                                                         rbn_s+128, rbn_b+128, b2);
    k_conv<128,2,2,1><<<dim3(512, B_), blk, 0, stream>>>(b2, wts+OFF_C4, c4_b,
                                                         rbn_s+256, rbn_b+256, b3);
    k_resA<<<dim3(512, B_), blk, 0, stream>>>(xb, b1, b2, b3, wts+OFF_C1, c1_b,
                                              wts+OFF_C5, c5_b, rbn_s+384, rbn_b+384, outA);
    k_pw3<<<dim3(512, B_), blk, 0, stream>>>(outA, wts+OFF_PW, p_b, pbn_s, pbn_b, b1);
    wn_kernel<<<dim3(1600, B_), blk, 0, stream>>>(xyz, w1_w, w1_b, w2_w, w2_b, w3_w, w3_b,
                                                  wbn1_s, wbn1_b, wbn2_s, wbn2_b,
                                                  wbn3_s, wbn3_b, b2);
    k_yfused<<<dim3(256, B_), dim3(512), 0, stream>>>(b1, b2, wts+OFF_LIN, lin_b,
                                                      pbn_s+384, pbn_b+384, outB);
}

// Round 9
// 570.023 us; speedup vs baseline: 1.1933x; 1.1933x over previous
//
#include <hip/hip_runtime.h>
#include <hip/hip_bf16.h>

typedef __hip_bfloat16 bf16;
typedef unsigned short u16;
typedef unsigned int   u32;

#define B_   2
#define CIN_ 64
#define C_   128
#define H_   64
#define W_   1024
#define HW_  (H_*W_)
#define H2_  32
#define W2_  512
#define HW2_ (H2_*W2_)

typedef __attribute__((ext_vector_type(8))) short bf16x8;
typedef __attribute__((ext_vector_type(4))) float f32x4;

// Transformed bf16 weights (row-major, k-contiguous per co row).
#define OFF_C2  0
#define OFF_C3  73728
#define OFF_C4  221184
#define OFF_C5  286720
#define OFF_C1  335872
#define OFF_PW  344064
#define OFF_LIN 393216
#define WTS_TOT 655360
__device__ __align__(16) u16 g_wts[WTS_TOT];
// Module-owned activation buffers (both batches live).
// b1/b2/b3 hold conv-pipeline activations in PX-MAJOR [hw][128] bf16 layout.
// (b1 later reused for h in [c][hw]; b2 later reused for wn.)
__device__ __align__(16) u16 g_b1[(size_t)B_*C_*HW_];      // 32 MiB
__device__ __align__(16) u16 g_b2[(size_t)B_*C_*HW_];      // 32 MiB
__device__ __align__(16) u16 g_b3[(size_t)B_*C_*HW_];      // 32 MiB
__device__ __align__(16) u16 g_xb[(size_t)B_*HW_*CIN_];    // 16 MiB (xb [hw][64])

__device__ __forceinline__ float bits2f(u16 u){
    u32 x = ((u32)u) << 16; float f; __builtin_memcpy(&f, &x, 4); return f;
}
__device__ __forceinline__ u16 f2bits(float v){
    bf16 h = __float2bfloat16(v); u16 u; __builtin_memcpy(&u, &h, 2); return u;
}
__device__ __forceinline__ float lrelu(float v){ return v > 0.f ? v : 0.01f*v; }
__device__ __forceinline__ float relu (float v){ return v > 0.f ? v : 0.f; }

// ---------------------------------------------------------------------------
// MFMA tile machinery. Tile M=128 (co) x N=128 (pix), K-step 32.
// A/B LDS rows stride LSTR=40 u16 (+16B pad, odd 16B-granule count).
// R8 lesson: A-fragments from global on the MFMA critical path regress
// (L2 gather latency, 4 waves can't hide it) — A stays in LDS here.
// ---------------------------------------------------------------------------
#define LSTR 40
#define PSTR 136   // full-K (128) B stride for k_pw3 / k_yfused
#define TSTR 136   // epilogue transpose tile stride (16B-aligned rows)

__device__ __forceinline__ void stage_A(u16* As, const u16* w, int wstr, int col0, int tid)
{
#pragma unroll
    for (int r = 0; r < 2; r++) {
        int e = tid + 256*r;
        int co = e >> 2, ch = e & 3;
        *(uint4*)&As[co*LSTR + ch*8] = *(const uint4*)&w[co*wstr + col0 + ch*8];
    }
}

// B-tile staging from px-major activations: row j = pixel, k = channels
// (k-contiguous in memory -> pure vector copy, no transpose).
__device__ __forceinline__ void stage_B_pm(u16* Bs, const u16* src, int rowStride,
                                           int kc, int tid)
{
#pragma unroll
    for (int r = 0; r < 2; r++) {
        int e = tid + 256*r;
        int j = e >> 2, g = e & 3;
        *(uint4*)&Bs[j*LSTR + g*8] =
            *(const uint4*)&src[(size_t)j*rowStride + kc*32 + g*8];
    }
}

__device__ __forceinline__ void mfma_step_s(const u16* As, const u16* Bs, int bstr, int koff,
                                            int lane, int wm, int wn_, f32x4 acc[4][4])
{
    const int quad = lane >> 4, l15 = lane & 15;
    bf16x8 a[4], b[4];
#pragma unroll
    for (int i = 0; i < 4; i++)
        a[i] = *(const bf16x8*)&As[(wm*64 + i*16 + l15)*LSTR + quad*8];
#pragma unroll
    for (int j = 0; j < 4; j++)
        b[j] = *(const bf16x8*)&Bs[(wn_*64 + j*16 + l15)*bstr + koff + quad*8];
#pragma unroll
    for (int i = 0; i < 4; i++)
#pragma unroll
        for (int j = 0; j < 4; j++)
            acc[i][j] = __builtin_amdgcn_mfma_f32_16x16x32_bf16(a[i], b[j], acc[i][j], 0, 0, 0);
}

__device__ __forceinline__ void mfma_step(const u16* As, const u16* Bs,
                                          int lane, int wm, int wn_, f32x4 acc[4][4])
{
    mfma_step_s(As, Bs, LSTR, 0, lane, wm, wn_, acc);
}

__device__ __forceinline__ void init_bias(f32x4 acc[4][4], const float* bias, int wm, int lane)
{
    const int quad = lane >> 4;
#pragma unroll
    for (int i = 0; i < 4; i++)
#pragma unroll
        for (int r = 0; r < 4; r++) {
            float bv = bias[wm*64 + i*16 + quad*4 + r];
#pragma unroll
            for (int j = 0; j < 4; j++) acc[i][j][r] = bv;
        }
}

// ---------------------------------------------------------------------------
// x transpose: fp32 [64][HW] -> bf16 [HW][64] (enables vector B-staging in
// c2 conv and resA shortcut). grid (512, B_), block 256.
// ---------------------------------------------------------------------------
#define XTS 70
__global__ __launch_bounds__(256)
void k_xtrans(const float* __restrict__ x0, u16* __restrict__ xb0)
{
    __shared__ __align__(16) u16 T[128*XTS];
    const int tid = threadIdx.x;
    const float* x = x0 + (size_t)blockIdx.y*CIN_*HW_;
    u16* xb = xb0 + (size_t)blockIdx.y*HW_*CIN_;
    const int pix0 = blockIdx.x * 128;
#pragma unroll
    for (int r = 0; r < 8; r++) {
        int e = tid + 256*r;               // 2048 items: 64 c x 32 px-groups
        int c = e >> 5, p4 = (e & 31)*4;
        float4 v = *(const float4*)&x[(size_t)c*HW_ + pix0 + p4];
        T[(p4+0)*XTS + c] = f2bits(v.x);
        T[(p4+1)*XTS + c] = f2bits(v.y);
        T[(p4+2)*XTS + c] = f2bits(v.z);
        T[(p4+3)*XTS + c] = f2bits(v.w);
    }
    __syncthreads();
#pragma unroll
    for (int r = 0; r < 4; r++) {
        int e = tid + 256*r;               // 1024 granules: 128 px x 8
        int p = e >> 3, g = e & 7;
        // rows are XTS*2=140B apart; granule addr 8B-aligned -> copy as 2 uint2
        const u16* s = &T[p*XTS + g*8];
        u16* d = &xb[(size_t)(pix0+p)*CIN_ + g*8];
        *(uint2*)&d[0] = *(const uint2*)&s[0];
        *(uint2*)&d[4] = *(const uint2*)&s[4];
    }
}

// ---------------------------------------------------------------------------
// Conv as shift-decomposed GEMM over px-major activations, dx-hoisted:
// for each tap-row dy, stage ONE wide B window [136 px][32 k] per kc plus the
// KS taps' A-tiles, then run all KS dx-taps from LDS (B row offset d*DIL).
// Barrier-pairs: KS*(CI/32) instead of KS*KS*(CI/32); Bs staging / KS.
// grid (512, B_), block 256.  in: [hw][CI] bf16, out: [hw][128] bf16.
// ---------------------------------------------------------------------------
template<int CI, int KS, int DIL, int PAD>
__global__ __launch_bounds__(256)
void k_conv(const u16* __restrict__ in0, const u16* __restrict__ wT,
            const float* __restrict__ bias, const float* __restrict__ bns,
            const float* __restrict__ bnb, u16* __restrict__ out0)
{
    constexpr int WTOT = 136;                  // wide window rows (>=128+(KS-1)*DIL)
    constexpr int ASZ  = KS*128*LSTR;
    constexpr int SSZ  = (ASZ + WTOT*LSTR) > 128*TSTR ? (ASZ + WTOT*LSTR) : 128*TSTR;
    __shared__ __align__(16) u16 S[SSZ];
    u16* As = S;                               // [KS][128 co][LSTR]
    u16* Bs = S + ASZ;                         // [WTOT px][LSTR]
    const int tid = threadIdx.x, lane = tid & 63, wave = tid >> 6;
    const int wm = wave & 1, wn_ = wave >> 1;
    const int quad = lane >> 4, l15 = lane & 15;
    const u16* in = in0 + (size_t)blockIdx.y*HW_*CI;
    u16* out = out0 + (size_t)blockIdx.y*HW_*C_;
    const int pix0 = blockIdx.x * 128;
    const int y = pix0 >> 10, x0 = pix0 & 1023;

    f32x4 acc[4][4];
    init_bias(acc, bias, wm, lane);

    for (int dyi = 0; dyi < KS; dyi++) {
        int yy = y + dyi*DIL - PAD;
        if (yy < 0 || yy >= H_) continue;      // block-uniform (tile = one row)
        const u16* srow = in + (size_t)yy*W_*CI;
        for (int kc = 0; kc < CI/32; kc++) {
            __syncthreads();                   // prev pair's MFMA done with As/Bs
            // Stage A-tiles for all KS dx taps of this row: KS*512 granules
            for (int e = tid; e < KS*512; e += 256) {
                int d = e >> 9, rem = e & 511;
                int co = rem >> 2, ch = rem & 3;
                *(uint4*)&As[d*128*LSTR + co*LSTR + ch*8] =
                    *(const uint4*)&wT[(size_t)(dyi*KS + d)*128*CI + co*CI + kc*32 + ch*8];
            }
            // Stage wide B window: 136 px x 32 ch (x = x0 - PAD + wpx)
            for (int e = tid; e < WTOT*4; e += 256) {
                int wpx = e >> 2, g = e & 3;
                int xx = x0 - PAD + wpx;
                uint4 v = make_uint4(0u, 0u, 0u, 0u);
                if ((unsigned)xx < (unsigned)W_)
                    v = *(const uint4*)&srow[(size_t)xx*CI + kc*32 + g*8];
                *(uint4*)&Bs[wpx*LSTR + g*8] = v;
            }
            __syncthreads();                   // As + Bs ready
#pragma unroll
            for (int d = 0; d < KS; d++) {
                bf16x8 a[4], bb[4];
#pragma unroll
                for (int i = 0; i < 4; i++)
                    a[i] = *(const bf16x8*)&As[d*128*LSTR + (wm*64 + i*16 + l15)*LSTR + quad*8];
#pragma unroll
                for (int j = 0; j < 4; j++)
                    bb[j] = *(const bf16x8*)&Bs[(wn_*64 + j*16 + l15 + d*DIL)*LSTR + quad*8];
#pragma unroll
                for (int i = 0; i < 4; i++)
#pragma unroll
                    for (int j = 0; j < 4; j++)
                        acc[i][j] = __builtin_amdgcn_mfma_f32_16x16x32_bf16(a[i], bb[j], acc[i][j], 0, 0, 0);
            }
        }
    }
    // Epilogue: bn+lrelu -> LDS transpose tile [px][co] -> vector px-major store
    u16* T = S;
    __syncthreads();                           // all waves done reading As/Bs
#pragma unroll
    for (int i = 0; i < 4; i++)
#pragma unroll
        for (int r = 0; r < 4; r++) {
            int co = wm*64 + i*16 + quad*4 + r;
            float ss = bns[co], tt = bnb[co];
#pragma unroll
            for (int j = 0; j < 4; j++) {
                float v = lrelu(acc[i][j][r]) * ss + tt;
                T[(wn_*64 + j*16 + l15)*TSTR + co] = f2bits(v);
            }
        }
    __syncthreads();
#pragma unroll
    for (int r = 0; r < 8; r++) {
        int e = tid + 256*r;
        int px = e >> 4, g = e & 15;
        *(uint4*)&out[(size_t)(pix0+px)*C_ + g*8] = *(const uint4*)&T[px*TSTR + g*8];
    }
}

// ---------------------------------------------------------------------------
// resA = bn3(lrelu(c5_w@[A1;A2;A3] + c5_b)) + lrelu(c1_w@x + c1_b)  (fp32 out)
// Inputs xb/A1/A2/A3 in px-major layout; output stays [C][HW] fp32 (required).
// (R7-proven structure.)
// ---------------------------------------------------------------------------
__global__ __launch_bounds__(256)
void k_resA(const u16* __restrict__ xb0, const u16* __restrict__ a10,
            const u16* __restrict__ a20, const u16* __restrict__ a30,
            const u16* __restrict__ wc1, const float* __restrict__ c1b,
            const u16* __restrict__ wc5, const float* __restrict__ c5b,
            const float* __restrict__ s3, const float* __restrict__ b3,
            float* __restrict__ out0)
{
    __shared__ __align__(16) u16 As[128*LSTR];
    __shared__ __align__(16) u16 Bs[128*LSTR];
    const int tid = threadIdx.x, lane = tid & 63, wave = tid >> 6;
    const int wm = wave & 1, wn_ = wave >> 1;
    const int b = blockIdx.y;
    const u16* xb = xb0 + (size_t)b*HW_*CIN_;
    const u16* aa[3] = { a10 + (size_t)b*HW_*C_, a20 + (size_t)b*HW_*C_, a30 + (size_t)b*HW_*C_ };
    float* out = out0 + (size_t)b*C_*HW_;
    const int pix0 = blockIdx.x * 128;
    const int quad = lane >> 4, l15 = lane & 15;

    // shortcut: K=64 over xb
    f32x4 acc[4][4];
    init_bias(acc, c1b, wm, lane);
    for (int kc = 0; kc < 2; kc++) {
        stage_A(As, wc1, 64, kc*32, tid);
        stage_B_pm(Bs, xb + (size_t)pix0*CIN_, CIN_, kc, tid);
        __syncthreads();
        mfma_step(As, Bs, lane, wm, wn_, acc);
        __syncthreads();
    }
    float sc[4][4][4];
#pragma unroll
    for (int i = 0; i < 4; i++)
#pragma unroll
        for (int j = 0; j < 4; j++)
#pragma unroll
            for (int r = 0; r < 4; r++) sc[i][j][r] = lrelu(acc[i][j][r]);

    // main: K=384 over [A1;A2;A3]
    init_bias(acc, c5b, wm, lane);
    for (int s = 0; s < 3; s++) {
        const u16* src = aa[s] + (size_t)pix0*C_;
        for (int kc = 0; kc < 4; kc++) {
            stage_A(As, wc5, 384, s*128 + kc*32, tid);
            stage_B_pm(Bs, src, C_, kc, tid);
            __syncthreads();
            mfma_step(As, Bs, lane, wm, wn_, acc);
            __syncthreads();
        }
    }
#pragma unroll
    for (int i = 0; i < 4; i++)
#pragma unroll
        for (int r = 0; r < 4; r++) {
            int co = wm*64 + i*16 + quad*4 + r;
            float ss = s3[co], tt = b3[co];
#pragma unroll
            for (int j = 0; j < 4; j++) {
                float v = lrelu(acc[i][j][r]) * ss + tt + sc[i][j][r];
                out[co*HW_ + pix0 + wn_*64 + j*16 + l15] = v;
            }
        }
}

// ---------------------------------------------------------------------------
// Fused 3-layer pointwise MLP: h = relu(bn(W3 relu(bn(W2 relu(bn(W1 resA)))))).
// One block owns 128 pixels end-to-end; inter-layer activations in LDS.
// (R7-proven structure.)
// ---------------------------------------------------------------------------
__global__ __launch_bounds__(256)
void k_pw3(const float* __restrict__ in0, const u16* __restrict__ w,
           const float* __restrict__ pb, const float* __restrict__ ps,
           const float* __restrict__ pbb, u16* __restrict__ out0)
{
    __shared__ __align__(16) u16 As[128*LSTR];
    __shared__ __align__(16) u16 B0[128*PSTR];
    __shared__ __align__(16) u16 B1[128*PSTR];
    const int tid = threadIdx.x, lane = tid & 63, wave = tid >> 6;
    const int wm = wave & 1, wn_ = wave >> 1;
    const int b = blockIdx.y;
    const float* in = in0 + (size_t)b*C_*HW_;
    u16* out = out0 + (size_t)b*C_*HW_;
    const int pix0 = blockIdx.x * 128;
    const int quad = lane >> 4, l15 = lane & 15;

    // Stage B0 [pix][k] from fp32 resA (vector loads along pix, scatter to LDS)
    for (int e = tid; e < 128*32; e += 256) {
        int kk = e >> 5, j4 = (e & 31)*4;
        float4 v = *(const float4*)&in[kk*HW_ + pix0 + j4];
        u16* d = &B0[j4*PSTR + kk];
        d[0]      = f2bits(v.x);
        d[PSTR]   = f2bits(v.y);
        d[2*PSTR] = f2bits(v.z);
        d[3*PSTR] = f2bits(v.w);
    }

    u16* Bc = B0;
    u16* Bn = B1;
#pragma unroll
    for (int L = 0; L < 3; L++) {
        f32x4 acc[4][4];
        init_bias(acc, pb + L*128, wm, lane);
        for (int kc = 0; kc < 4; kc++) {
            stage_A(As, w + L*16384, 128, kc*32, tid);
            __syncthreads();                       // As + (Bc writes) visible
            mfma_step_s(As, Bc, PSTR, kc*32, lane, wm, wn_, acc);
            __syncthreads();                       // done reading As
        }
        const float* ss = ps + L*128;
        const float* tt = pbb + L*128;
        if (L < 2) {
#pragma unroll
            for (int i = 0; i < 4; i++)
#pragma unroll
                for (int r = 0; r < 4; r++) {
                    int co = wm*64 + i*16 + quad*4 + r;
                    float s1 = ss[co], t1 = tt[co];
#pragma unroll
                    for (int j = 0; j < 4; j++) {
                        float v = relu(acc[i][j][r] * s1 + t1);
                        Bn[(wn_*64 + j*16 + l15)*PSTR + co] = f2bits(v);
                    }
                }
            u16* t = Bc; Bc = Bn; Bn = t;
        } else {
#pragma unroll
            for (int i = 0; i < 4; i++)
#pragma unroll
                for (int r = 0; r < 4; r++) {
                    int co = wm*64 + i*16 + quad*4 + r;
                    float s1 = ss[co], t1 = tt[co];
#pragma unroll
                    for (int j = 0; j < 4; j++) {
                        float v = relu(acc[i][j][r] * s1 + t1);
                        out[co*HW_ + pix0 + wn_*64 + j*16 + l15] = f2bits(v);
                    }
                }
        }
    }
}

// ---------------------------------------------------------------------------
// WeightNet: xyz fp32 -> bf16 [16,25,H2,W2] per batch.
// ---------------------------------------------------------------------------
__global__ __launch_bounds__(256)
void wn_kernel(const float* __restrict__ xyz0,
               const float* __restrict__ w1w, const float* __restrict__ w1b,
               const float* __restrict__ w2w, const float* __restrict__ w2b,
               const float* __restrict__ w3w, const float* __restrict__ w3b,
               const float* __restrict__ s1, const float* __restrict__ bb1,
               const float* __restrict__ s2, const float* __restrict__ bb2,
               const float* __restrict__ s3, const float* __restrict__ bb3,
               u16* __restrict__ out0)
{
    const float* xyz = xyz0 + (size_t)blockIdx.y*3*HW_;
    u16* out = out0 + (size_t)blockIdx.y*400*HW2_;
    int idx = blockIdx.x*256 + threadIdx.x;
    int j = idx & (W2_-1); int t = idx >> 9;
    int i = t & (H2_-1);   int k = t >> 5;
    int kh = k / 5, kw = k - kh*5;
    int yy = 2*i + kh - 2, xx = 2*j + kw - 2;
    bool inr = (yy >= 0 && yy < H_ && xx >= 0 && xx < W_);

    float g[3];
#pragma unroll
    for (int c = 0; c < 3; c++) {
        float ctr = xyz[c*HW_ + (2*i)*W_ + 2*j];
        float v = inr ? xyz[c*HW_ + yy*W_ + xx] : 0.f;
        g[c] = v - ctr;
    }
    float a1[8];
#pragma unroll
    for (int n = 0; n < 8; n++) {
        float v = w1b[n];
#pragma unroll
        for (int c = 0; c < 3; c++) v += w1w[n*3 + c] * g[c];
        a1[n] = relu(v * s1[n] + bb1[n]);
    }
    float a2[8];
#pragma unroll
    for (int n = 0; n < 8; n++) {
        float v = w2b[n];
#pragma unroll
        for (int m = 0; m < 8; m++) v += w2w[n*8 + m] * a1[m];
        a2[n] = relu(v * s2[n] + bb2[n]);
    }
#pragma unroll
    for (int n = 0; n < 16; n++) {
        float v = w3b[n];
#pragma unroll
        for (int m = 0; m < 8; m++) v += w3w[n*8 + m] * a2[m];
        v = relu(v * s3[n] + bb3[n]);
        out[(n*25 + k)*HW2_ + i*W2_ + j] = f2bits(v);
    }
}

// ---------------------------------------------------------------------------
// Fused ycompute + linear head (R7-proven; unchanged):
//   y[px][c*16+n] = sum_k unf(h)[c][k][px] * wn[n][k][px]     (bf16, LDS only)
//   resB[co][px]  = relu(bn(lin_w @ y + lin_b))               (fp32 out)
// ---------------------------------------------------------------------------
__global__ __launch_bounds__(512)
void k_yfused(const u16* __restrict__ h0, const u16* __restrict__ wn0,
              const u16* __restrict__ w, const float* __restrict__ bias,
              const float* __restrict__ bns, const float* __restrict__ bnb,
              float* __restrict__ out0)
{
    __shared__ __align__(16) float slab[40*148];   // 23.7 KB (8 cc * 5 rr rows)
    __shared__ __align__(16) u16 Bs[64*PSTR];      // 17.4 KB (y sub-tile)
    const int tid = threadIdx.x;
    const int bx = blockIdx.x;
    const int j0 = (bx & 7) * 64;
    const int i2 = bx >> 3;
    const int b  = blockIdx.y;
    const u16* h  = h0  + (size_t)b*C_*HW_;
    const u16* wn = wn0 + (size_t)b*400*HW2_;
    float* out = out0 + (size_t)b*C_*HW2_;

    // phase-1 roles: n fast (16-way broadcast group), pxq = px-pair index
    const int n = tid & 15, pxq = tid >> 4;        // pxq 0..31
    // phase-2 roles
    const int lane = tid & 63, wave = tid >> 6;
    const int wm4 = wave & 3, wnp = wave >> 2;     // 4x32 co, 2x32 px
    const int quad = lane >> 4, l15 = lane & 15;

    // wn for this thread's (n, px-pair): 25 taps f32 in regs (50 VGPR)
    float wnreg[25][2];
    {
        const u16* wb = wn + (n*25)*HW2_ + i2*W2_ + j0 + pxq*2;
#pragma unroll
        for (int k = 0; k < 25; k++) {
            u32 t = *(const u32*)(wb + k*HW2_);
            wnreg[k][0] = bits2f((u16)(t & 0xffff));
            wnreg[k][1] = bits2f((u16)(t >> 16));
        }
    }

    // A-fragment lane base offsets into lin_w [128][2048]
    const int bA0 = (wm4*32 +  0 + l15)*2048 + quad*8;
    const int bA1 = (wm4*32 + 16 + l15)*2048 + quad*8;

    f32x4 acc[2][2];
#pragma unroll
    for (int i = 0; i < 2; i++)
#pragma unroll
        for (int r = 0; r < 4; r++) {
            float bv = bias[wm4*32 + i*16 + quad*4 + r];
            acc[i][0][r] = bv;
            acc[i][1][r] = bv;
        }

    for (int c0 = 0; c0 < 128; c0 += 8) {
        __syncthreads();                           // prev MFMA done with Bs; slab free
        // Fill slab: 8 cc x 5 rr x 18 uint4-groups
        for (int e = tid; e < 720; e += 512) {
            int cc = e / 90, rem = e - cc*90;
            int rr = rem / 18, g = rem - rr*18;
            int yy = 2*i2 + rr - 2;
            int xs0 = 2*j0 - 8 + 8*g;              // 16B-aligned global offset
            float f[8];
            if ((unsigned)yy < (unsigned)H_ && (unsigned)xs0 <= (unsigned)(W_-8)) {
                uint4 v = *(const uint4*)&h[(c0+cc)*HW_ + yy*W_ + xs0];
                f[0] = bits2f((u16)(v.x & 0xffff)); f[1] = bits2f((u16)(v.x >> 16));
                f[2] = bits2f((u16)(v.y & 0xffff)); f[3] = bits2f((u16)(v.y >> 16));
                f[4] = bits2f((u16)(v.z & 0xffff)); f[5] = bits2f((u16)(v.z >> 16));
                f[6] = bits2f((u16)(v.w & 0xffff)); f[7] = bits2f((u16)(v.w >> 16));
            } else if ((unsigned)yy < (unsigned)H_) {
#pragma unroll
                for (int m = 0; m < 8; m++) {
                    int xs = xs0 + m;
                    f[m] = ((unsigned)xs < (unsigned)W_)
                         ? bits2f(h[(c0+cc)*HW_ + yy*W_ + xs]) : 0.f;
                }
            } else {
#pragma unroll
                for (int m = 0; m < 8; m++) f[m] = 0.f;
            }
            float* d = &slab[(cc*5 + rr)*148 + 2 + 8*g];
            *(float2*)(d+0) = make_float2(f[0], f[1]);
            *(float2*)(d+2) = make_float2(f[2], f[3]);
            *(float2*)(d+4) = make_float2(f[4], f[5]);
            *(float2*)(d+6) = make_float2(f[6], f[7]);
        }
        // Issue this chunk's A-fragments (global->reg; L2-resident lin_w)
        bf16x8 af0[4], af1[4];
#pragma unroll
        for (int kc = 0; kc < 4; kc++) {
            af0[kc] = *(const bf16x8*)&w[bA0 + c0*16 + kc*32];
            af1[kc] = *(const bf16x8*)&w[bA1 + c0*16 + kc*32];
        }
        __syncthreads();                           // slab ready
        // y-compute into Bs [px][cc*16+n]
#pragma unroll 2
        for (int cc = 0; cc < 8; cc++) {
            float yv0 = 0.f, yv1 = 0.f;
#pragma unroll
            for (int rr = 0; rr < 5; rr++) {
                const float* fr = &slab[(cc*5 + rr)*148 + 8 + 4*pxq];
                float4 A  = *(const float4*)fr;
                float4 Bv = *(const float4*)(fr + 4);
                yv0 += A.x*wnreg[rr*5+0][0] + A.y*wnreg[rr*5+1][0]
                     + A.z*wnreg[rr*5+2][0] + A.w*wnreg[rr*5+3][0]
                     + Bv.x*wnreg[rr*5+4][0];
                yv1 += A.z*wnreg[rr*5+0][1] + A.w*wnreg[rr*5+1][1]
                     + Bv.x*wnreg[rr*5+2][1] + Bv.y*wnreg[rr*5+3][1]
                     + Bv.z*wnreg[rr*5+4][1];
            }
            Bs[(2*pxq)  *PSTR + cc*16 + n] = f2bits(yv0);
            Bs[(2*pxq+1)*PSTR + cc*16 + n] = f2bits(yv1);
        }
        __syncthreads();                           // Bs ready
        // MFMA: A from regs, B from Bs
#pragma unroll
        for (int kc = 0; kc < 4; kc++) {
            bf16x8 b0 = *(const bf16x8*)&Bs[(wnp*32 +  0 + l15)*PSTR + kc*32 + quad*8];
            bf16x8 b1 = *(const bf16x8*)&Bs[(wnp*32 + 16 + l15)*PSTR + kc*32 + quad*8];
            acc[0][0] = __builtin_amdgcn_mfma_f32_16x16x32_bf16(af0[kc], b0, acc[0][0], 0, 0, 0);
            acc[0][1] = __builtin_amdgcn_mfma_f32_16x16x32_bf16(af0[kc], b1, acc[0][1], 0, 0, 0);
            acc[1][0] = __builtin_amdgcn_mfma_f32_16x16x32_bf16(af1[kc], b0, acc[1][0], 0, 0, 0);
            acc[1][1] = __builtin_amdgcn_mfma_f32_16x16x32_bf16(af1[kc], b1, acc[1][1], 0, 0, 0);
        }
    }
    // epilogue: bn + relu -> fp32 resB
#pragma unroll
    for (int i = 0; i < 2; i++)
#pragma unroll
        for (int r = 0; r < 4; r++) {
            int co = wm4*32 + i*16 + quad*4 + r;
            float ss = bns[co], tt = bnb[co];
#pragma unroll
            for (int j = 0; j < 2; j++) {
                float v = relu(acc[i][j][r] * ss + tt);
                out[co*HW2_ + i2*W2_ + j0 + wnp*32 + j*16 + l15] = v;
            }
        }
}

// ---------------------------------------------------------------------------
// Weight transform: fp32 -> bf16 g_wts (k-contiguous layouts).
// ---------------------------------------------------------------------------
__global__ __launch_bounds__(256)
void k_wtrans(const float* __restrict__ c2w, const float* __restrict__ c3w,
              const float* __restrict__ c4w, const float* __restrict__ c5w,
              const float* __restrict__ c1w, const float* __restrict__ pw,
              const float* __restrict__ linw)
{
    int i = blockIdx.x*256 + threadIdx.x;
    if (i >= WTS_TOT) return;
    float v;
    if (i < OFF_C3) {
        int p = i / 8192, rem = i - p*8192;
        int co = rem >> 6, ci = rem & 63;
        v = c2w[(co*64 + ci)*9 + p];
    } else if (i < OFF_C4) {
        int t = i - OFF_C3;
        int p = t / 16384, rem = t - p*16384;
        int co = rem >> 7, ci = rem & 127;
        v = c3w[(co*128 + ci)*9 + p];
    } else if (i < OFF_C5) {
        int t = i - OFF_C4;
        int p = t / 16384, rem = t - p*16384;
        int co = rem >> 7, ci = rem & 127;
        v = c4w[(co*128 + ci)*4 + p];
    } else if (i < OFF_C1)  v = c5w[i - OFF_C5];
    else if (i < OFF_PW)    v = c1w[i - OFF_C1];
    else if (i < OFF_LIN)   v = pw[i - OFF_PW];
    else                    v = linw[i - OFF_LIN];
    g_wts[i] = f2bits(v);
}

// ---------------------------------------------------------------------------
extern "C" void kernel_launch(void* const* d_in, const int* in_sizes, int n_in,
                              void* d_out, int out_size, void* d_ws, size_t ws_size,
                              hipStream_t stream)
{
    const float* x     = (const float*)d_in[0];
    const float* xyz   = (const float*)d_in[1];
    const float* c1_w  = (const float*)d_in[2];
    const float* c1_b  = (const float*)d_in[3];
    const float* c2_w  = (const float*)d_in[4];
    const float* c2_b  = (const float*)d_in[5];
    const float* c3_w  = (const float*)d_in[6];
    const float* c3_b  = (const float*)d_in[7];
    const float* c4_w  = (const float*)d_in[8];
    const float* c4_b  = (const float*)d_in[9];
    const float* c5_w  = (const float*)d_in[10];
    const float* c5_b  = (const float*)d_in[11];
    const float* rbn_s = (const float*)d_in[12];
    const float* rbn_b = (const float*)d_in[13];
    const float* p_w   = (const float*)d_in[14];
    const float* p_b   = (const float*)d_in[15];
    const float* pbn_s = (const float*)d_in[16];
    const float* pbn_b = (const float*)d_in[17];
    const float* lin_w = (const float*)d_in[18];
    const float* lin_b = (const float*)d_in[19];
    const float* w1_w  = (const float*)d_in[20];
    const float* w1_b  = (const float*)d_in[21];
    const float* w2_w  = (const float*)d_in[22];
    const float* w2_b  = (const float*)d_in[23];
    const float* w3_w  = (const float*)d_in[24];
    const float* w3_b  = (const float*)d_in[25];
    const float* wbn1_s = (const float*)d_in[26];
    const float* wbn1_b = (const float*)d_in[27];
    const float* wbn2_s = (const float*)d_in[28];
    const float* wbn2_b = (const float*)d_in[29];
    const float* wbn3_s = (const float*)d_in[30];
    const float* wbn3_b = (const float*)d_in[31];

    float* outB = (float*)d_out;                     // [2,128,32,512] fp32
    float* outA = outB + (size_t)B_*C_*HW2_;         // [2,128,64,1024] fp32

    u16 *wts, *b1, *b2, *b3, *xb;
    { void* p; hipGetSymbolAddress(&p, HIP_SYMBOL(g_wts)); wts = (u16*)p; }
    { void* p; hipGetSymbolAddress(&p, HIP_SYMBOL(g_b1));  b1  = (u16*)p; }
    { void* p; hipGetSymbolAddress(&p, HIP_SYMBOL(g_b2));  b2  = (u16*)p; }
    { void* p; hipGetSymbolAddress(&p, HIP_SYMBOL(g_b3));  b3  = (u16*)p; }
    { void* p; hipGetSymbolAddress(&p, HIP_SYMBOL(g_xb));  xb  = (u16*)p; }

    dim3 blk(256);

    k_wtrans<<<dim3((WTS_TOT + 255)/256), blk, 0, stream>>>(c2_w, c3_w, c4_w, c5_w,
                                                            c1_w, p_w, lin_w);
    k_xtrans<<<dim3(512, B_), blk, 0, stream>>>(x, xb);
    k_conv<64,3,1,1><<<dim3(512, B_), blk, 0, stream>>>(xb, wts+OFF_C2, c2_b,
                                                        rbn_s, rbn_b, b1);
    k_conv<128,3,2,2><<<dim3(512, B_), blk, 0, stream>>>(b1, wts+OFF_C3, c3_b,
                                                         rbn_s+128, rbn_b+128, b2);
    k_conv<128,2,2,1><<<dim3(512, B_), blk, 0, stream>>>(b2, wts+OFF_C4, c4_b,
                                                         rbn_s+256, rbn_b+256, b3);
    k_resA<<<dim3(512, B_), blk, 0, stream>>>(xb, b1, b2, b3, wts+OFF_C1, c1_b,
                                              wts+OFF_C5, c5_b, rbn_s+384, rbn_b+384, outA);
    k_pw3<<<dim3(512, B_), blk, 0, stream>>>(outA, wts+OFF_PW, p_b, pbn_s, pbn_b, b1);
    wn_kernel<<<dim3(1600, B_), blk, 0, stream>>>(xyz, w1_w, w1_b, w2_w, w2_b, w3_w, w3_b,
                                                  wbn1_s, wbn1_b, wbn2_s, wbn2_b,
                                                  wbn3_s, wbn3_b, b2);
    k_yfused<<<dim3(256, B_), dim3(512), 0, stream>>>(b1, b2, wts+OFF_LIN, lin_b,
                                                      pbn_s+384, pbn_b+384, outB);
}

// Round 10
// 528.208 us; speedup vs baseline: 1.2877x; 1.0792x over previous
//
#include <hip/hip_runtime.h>
#include <hip/hip_bf16.h>

typedef __hip_bfloat16 bf16;
typedef unsigned short u16;
typedef unsigned int   u32;

#define B_   2
#define CIN_ 64
#define C_   128
#define H_   64
#define W_   1024
#define HW_  (H_*W_)
#define H2_  32
#define W2_  512
#define HW2_ (H2_*W2_)

typedef __attribute__((ext_vector_type(8))) short bf16x8;
typedef __attribute__((ext_vector_type(4))) float f32x4;

// Transformed bf16 weights (row-major, k-contiguous per co row).
#define OFF_C2  0
#define OFF_C3  73728
#define OFF_C4  221184
#define OFF_C5  286720
#define OFF_C1  335872
#define OFF_PW  344064
#define OFF_LIN 393216
#define WTS_TOT 655360
__device__ __align__(16) u16 g_wts[WTS_TOT];
// Module-owned activation buffers (both batches live).
// b1/b2/b3 hold conv-pipeline activations in PX-MAJOR [hw][128] bf16 layout.
// (b1 later reused for h in [c][hw]; b2 later reused for wn.)
__device__ __align__(16) u16 g_b1[(size_t)B_*C_*HW_];      // 32 MiB
__device__ __align__(16) u16 g_b2[(size_t)B_*C_*HW_];      // 32 MiB
__device__ __align__(16) u16 g_b3[(size_t)B_*C_*HW_];      // 32 MiB
__device__ __align__(16) u16 g_xb[(size_t)B_*HW_*CIN_];    // 16 MiB (xb [hw][64])

__device__ __forceinline__ float bits2f(u16 u){
    u32 x = ((u32)u) << 16; float f; __builtin_memcpy(&f, &x, 4); return f;
}
__device__ __forceinline__ u16 f2bits(float v){
    bf16 h = __float2bfloat16(v); u16 u; __builtin_memcpy(&u, &h, 2); return u;
}
__device__ __forceinline__ float lrelu(float v){ return v > 0.f ? v : 0.01f*v; }
__device__ __forceinline__ float relu (float v){ return v > 0.f ? v : 0.f; }

// ---------------------------------------------------------------------------
// MFMA tile machinery. Tile M=128 (co) x N=128 (pix), K-step 32.
// A/B LDS rows stride LSTR=40 u16 (+16B pad, odd 16B-granule count).
// R8 lesson: A-fragments from global on the MFMA critical path regress
// (L2 gather latency, 4 waves can't hide it) — A stays in LDS for convs.
// ---------------------------------------------------------------------------
#define LSTR 40
#define PSTR 136   // full-K (128) B stride for k_pw3 / k_yfused
#define TSTR 136   // epilogue transpose tile stride (16B-aligned rows)

__device__ __forceinline__ void stage_A(u16* As, const u16* w, int wstr, int col0, int tid)
{
#pragma unroll
    for (int r = 0; r < 2; r++) {
        int e = tid + 256*r;
        int co = e >> 2, ch = e & 3;
        *(uint4*)&As[co*LSTR + ch*8] = *(const uint4*)&w[co*wstr + col0 + ch*8];
    }
}

// B-tile staging from px-major activations: row j = pixel, k = channels
// (k-contiguous in memory -> pure vector copy, no transpose).
__device__ __forceinline__ void stage_B_pm(u16* Bs, const u16* src, int rowStride,
                                           int kc, int tid)
{
#pragma unroll
    for (int r = 0; r < 2; r++) {
        int e = tid + 256*r;
        int j = e >> 2, g = e & 3;
        *(uint4*)&Bs[j*LSTR + g*8] =
            *(const uint4*)&src[(size_t)j*rowStride + kc*32 + g*8];
    }
}

__device__ __forceinline__ void mfma_step_s(const u16* As, const u16* Bs, int bstr, int koff,
                                            int lane, int wm, int wn_, f32x4 acc[4][4])
{
    const int quad = lane >> 4, l15 = lane & 15;
    bf16x8 a[4], b[4];
#pragma unroll
    for (int i = 0; i < 4; i++)
        a[i] = *(const bf16x8*)&As[(wm*64 + i*16 + l15)*LSTR + quad*8];
#pragma unroll
    for (int j = 0; j < 4; j++)
        b[j] = *(const bf16x8*)&Bs[(wn_*64 + j*16 + l15)*bstr + koff + quad*8];
#pragma unroll
    for (int i = 0; i < 4; i++)
#pragma unroll
        for (int j = 0; j < 4; j++)
            acc[i][j] = __builtin_amdgcn_mfma_f32_16x16x32_bf16(a[i], b[j], acc[i][j], 0, 0, 0);
}

__device__ __forceinline__ void mfma_step(const u16* As, const u16* Bs,
                                          int lane, int wm, int wn_, f32x4 acc[4][4])
{
    mfma_step_s(As, Bs, LSTR, 0, lane, wm, wn_, acc);
}

__device__ __forceinline__ void init_bias(f32x4 acc[4][4], const float* bias, int wm, int lane)
{
    const int quad = lane >> 4;
#pragma unroll
    for (int i = 0; i < 4; i++)
#pragma unroll
        for (int r = 0; r < 4; r++) {
            float bv = bias[wm*64 + i*16 + quad*4 + r];
#pragma unroll
            for (int j = 0; j < 4; j++) acc[i][j][r] = bv;
        }
}

// ---------------------------------------------------------------------------
// x transpose: fp32 [64][HW] -> bf16 [HW][64] (enables vector B-staging in
// c2 conv and resA shortcut). grid (512, B_), block 256.
// ---------------------------------------------------------------------------
#define XTS 70
__global__ __launch_bounds__(256)
void k_xtrans(const float* __restrict__ x0, u16* __restrict__ xb0)
{
    __shared__ __align__(16) u16 T[128*XTS];
    const int tid = threadIdx.x;
    const float* x = x0 + (size_t)blockIdx.y*CIN_*HW_;
    u16* xb = xb0 + (size_t)blockIdx.y*HW_*CIN_;
    const int pix0 = blockIdx.x * 128;
#pragma unroll
    for (int r = 0; r < 8; r++) {
        int e = tid + 256*r;               // 2048 items: 64 c x 32 px-groups
        int c = e >> 5, p4 = (e & 31)*4;
        float4 v = *(const float4*)&x[(size_t)c*HW_ + pix0 + p4];
        T[(p4+0)*XTS + c] = f2bits(v.x);
        T[(p4+1)*XTS + c] = f2bits(v.y);
        T[(p4+2)*XTS + c] = f2bits(v.z);
        T[(p4+3)*XTS + c] = f2bits(v.w);
    }
    __syncthreads();
#pragma unroll
    for (int r = 0; r < 4; r++) {
        int e = tid + 256*r;               // 1024 granules: 128 px x 8
        int p = e >> 3, g = e & 7;
        // rows are XTS*2=140B apart; granule addr 8B-aligned -> copy as 2 uint2
        const u16* s = &T[p*XTS + g*8];
        u16* d = &xb[(size_t)(pix0+p)*CIN_ + g*8];
        *(uint2*)&d[0] = *(const uint2*)&s[0];
        *(uint2*)&d[4] = *(const uint2*)&s[4];
    }
}

// ---------------------------------------------------------------------------
// Conv as shift-decomposed GEMM over px-major activations, dx-hoisted:
// for each tap-row dy, stage ONE wide B window [136 px][32 k] per kc plus the
// KS taps' A-tiles, then run all KS dx-taps from LDS (B row offset d*DIL).
// grid (512, B_), block 256.  in: [hw][CI] bf16, out: [hw][128] bf16.
// (R9-proven structure.)
// ---------------------------------------------------------------------------
template<int CI, int KS, int DIL, int PAD>
__global__ __launch_bounds__(256)
void k_conv(const u16* __restrict__ in0, const u16* __restrict__ wT,
            const float* __restrict__ bias, const float* __restrict__ bns,
            const float* __restrict__ bnb, u16* __restrict__ out0)
{
    constexpr int WTOT = 136;                  // wide window rows (>=128+(KS-1)*DIL)
    constexpr int ASZ  = KS*128*LSTR;
    constexpr int SSZ  = (ASZ + WTOT*LSTR) > 128*TSTR ? (ASZ + WTOT*LSTR) : 128*TSTR;
    __shared__ __align__(16) u16 S[SSZ];
    u16* As = S;                               // [KS][128 co][LSTR]
    u16* Bs = S + ASZ;                         // [WTOT px][LSTR]
    const int tid = threadIdx.x, lane = tid & 63, wave = tid >> 6;
    const int wm = wave & 1, wn_ = wave >> 1;
    const int quad = lane >> 4, l15 = lane & 15;
    const u16* in = in0 + (size_t)blockIdx.y*HW_*CI;
    u16* out = out0 + (size_t)blockIdx.y*HW_*C_;
    const int pix0 = blockIdx.x * 128;
    const int y = pix0 >> 10, x0 = pix0 & 1023;

    f32x4 acc[4][4];
    init_bias(acc, bias, wm, lane);

    for (int dyi = 0; dyi < KS; dyi++) {
        int yy = y + dyi*DIL - PAD;
        if (yy < 0 || yy >= H_) continue;      // block-uniform (tile = one row)
        const u16* srow = in + (size_t)yy*W_*CI;
        for (int kc = 0; kc < CI/32; kc++) {
            __syncthreads();                   // prev pair's MFMA done with As/Bs
            // Stage A-tiles for all KS dx taps of this row: KS*512 granules
            for (int e = tid; e < KS*512; e += 256) {
                int d = e >> 9, rem = e & 511;
                int co = rem >> 2, ch = rem & 3;
                *(uint4*)&As[d*128*LSTR + co*LSTR + ch*8] =
                    *(const uint4*)&wT[(size_t)(dyi*KS + d)*128*CI + co*CI + kc*32 + ch*8];
            }
            // Stage wide B window: 136 px x 32 ch (x = x0 - PAD + wpx)
            for (int e = tid; e < WTOT*4; e += 256) {
                int wpx = e >> 2, g = e & 3;
                int xx = x0 - PAD + wpx;
                uint4 v = make_uint4(0u, 0u, 0u, 0u);
                if ((unsigned)xx < (unsigned)W_)
                    v = *(const uint4*)&srow[(size_t)xx*CI + kc*32 + g*8];
                *(uint4*)&Bs[wpx*LSTR + g*8] = v;
            }
            __syncthreads();                   // As + Bs ready
#pragma unroll
            for (int d = 0; d < KS; d++) {
                bf16x8 a[4], bb[4];
#pragma unroll
                for (int i = 0; i < 4; i++)
                    a[i] = *(const bf16x8*)&As[d*128*LSTR + (wm*64 + i*16 + l15)*LSTR + quad*8];
#pragma unroll
                for (int j = 0; j < 4; j++)
                    bb[j] = *(const bf16x8*)&Bs[(wn_*64 + j*16 + l15 + d*DIL)*LSTR + quad*8];
#pragma unroll
                for (int i = 0; i < 4; i++)
#pragma unroll
                    for (int j = 0; j < 4; j++)
                        acc[i][j] = __builtin_amdgcn_mfma_f32_16x16x32_bf16(a[i], bb[j], acc[i][j], 0, 0, 0);
            }
        }
    }
    // Epilogue: bn+lrelu -> LDS transpose tile [px][co] -> vector px-major store
    u16* T = S;
    __syncthreads();                           // all waves done reading As/Bs
#pragma unroll
    for (int i = 0; i < 4; i++)
#pragma unroll
        for (int r = 0; r < 4; r++) {
            int co = wm*64 + i*16 + quad*4 + r;
            float ss = bns[co], tt = bnb[co];
#pragma unroll
            for (int j = 0; j < 4; j++) {
                float v = lrelu(acc[i][j][r]) * ss + tt;
                T[(wn_*64 + j*16 + l15)*TSTR + co] = f2bits(v);
            }
        }
    __syncthreads();
#pragma unroll
    for (int r = 0; r < 8; r++) {
        int e = tid + 256*r;
        int px = e >> 4, g = e & 15;
        *(uint4*)&out[(size_t)(pix0+px)*C_ + g*8] = *(const uint4*)&T[px*TSTR + g*8];
    }
}

// ---------------------------------------------------------------------------
// resA = bn3(lrelu(c5_w@[A1;A2;A3] + c5_b)) + lrelu(c1_w@x + c1_b)  (fp32 out)
// Inputs xb/A1/A2/A3 in px-major layout; output stays [C][HW] fp32 (required).
// (R7-proven structure.)
// ---------------------------------------------------------------------------
__global__ __launch_bounds__(256)
void k_resA(const u16* __restrict__ xb0, const u16* __restrict__ a10,
            const u16* __restrict__ a20, const u16* __restrict__ a30,
            const u16* __restrict__ wc1, const float* __restrict__ c1b,
            const u16* __restrict__ wc5, const float* __restrict__ c5b,
            const float* __restrict__ s3, const float* __restrict__ b3,
            float* __restrict__ out0)
{
    __shared__ __align__(16) u16 As[128*LSTR];
    __shared__ __align__(16) u16 Bs[128*LSTR];
    const int tid = threadIdx.x, lane = tid & 63, wave = tid >> 6;
    const int wm = wave & 1, wn_ = wave >> 1;
    const int b = blockIdx.y;
    const u16* xb = xb0 + (size_t)b*HW_*CIN_;
    const u16* aa[3] = { a10 + (size_t)b*HW_*C_, a20 + (size_t)b*HW_*C_, a30 + (size_t)b*HW_*C_ };
    float* out = out0 + (size_t)b*C_*HW_;
    const int pix0 = blockIdx.x * 128;
    const int quad = lane >> 4, l15 = lane & 15;

    // shortcut: K=64 over xb
    f32x4 acc[4][4];
    init_bias(acc, c1b, wm, lane);
    for (int kc = 0; kc < 2; kc++) {
        stage_A(As, wc1, 64, kc*32, tid);
        stage_B_pm(Bs, xb + (size_t)pix0*CIN_, CIN_, kc, tid);
        __syncthreads();
        mfma_step(As, Bs, lane, wm, wn_, acc);
        __syncthreads();
    }
    float sc[4][4][4];
#pragma unroll
    for (int i = 0; i < 4; i++)
#pragma unroll
        for (int j = 0; j < 4; j++)
#pragma unroll
            for (int r = 0; r < 4; r++) sc[i][j][r] = lrelu(acc[i][j][r]);

    // main: K=384 over [A1;A2;A3]
    init_bias(acc, c5b, wm, lane);
    for (int s = 0; s < 3; s++) {
        const u16* src = aa[s] + (size_t)pix0*C_;
        for (int kc = 0; kc < 4; kc++) {
            stage_A(As, wc5, 384, s*128 + kc*32, tid);
            stage_B_pm(Bs, src, C_, kc, tid);
            __syncthreads();
            mfma_step(As, Bs, lane, wm, wn_, acc);
            __syncthreads();
        }
    }
#pragma unroll
    for (int i = 0; i < 4; i++)
#pragma unroll
        for (int r = 0; r < 4; r++) {
            int co = wm*64 + i*16 + quad*4 + r;
            float ss = s3[co], tt = b3[co];
#pragma unroll
            for (int j = 0; j < 4; j++) {
                float v = lrelu(acc[i][j][r]) * ss + tt + sc[i][j][r];
                out[co*HW_ + pix0 + wn_*64 + j*16 + l15] = v;
            }
        }
}

// ---------------------------------------------------------------------------
// Fused 3-layer pointwise MLP: h = relu(bn(W3 relu(bn(W2 relu(bn(W1 resA)))))).
// One block owns 128 pixels end-to-end; inter-layer activations in LDS.
// (R7-proven structure.)
// ---------------------------------------------------------------------------
__global__ __launch_bounds__(256)
void k_pw3(const float* __restrict__ in0, const u16* __restrict__ w,
           const float* __restrict__ pb, const float* __restrict__ ps,
           const float* __restrict__ pbb, u16* __restrict__ out0)
{
    __shared__ __align__(16) u16 As[128*LSTR];
    __shared__ __align__(16) u16 B0[128*PSTR];
    __shared__ __align__(16) u16 B1[128*PSTR];
    const int tid = threadIdx.x, lane = tid & 63, wave = tid >> 6;
    const int wm = wave & 1, wn_ = wave >> 1;
    const int b = blockIdx.y;
    const float* in = in0 + (size_t)b*C_*HW_;
    u16* out = out0 + (size_t)b*C_*HW_;
    const int pix0 = blockIdx.x * 128;
    const int quad = lane >> 4, l15 = lane & 15;

    // Stage B0 [pix][k] from fp32 resA (vector loads along pix, scatter to LDS)
    for (int e = tid; e < 128*32; e += 256) {
        int kk = e >> 5, j4 = (e & 31)*4;
        float4 v = *(const float4*)&in[kk*HW_ + pix0 + j4];
        u16* d = &B0[j4*PSTR + kk];
        d[0]      = f2bits(v.x);
        d[PSTR]   = f2bits(v.y);
        d[2*PSTR] = f2bits(v.z);
        d[3*PSTR] = f2bits(v.w);
    }

    u16* Bc = B0;
    u16* Bn = B1;
#pragma unroll
    for (int L = 0; L < 3; L++) {
        f32x4 acc[4][4];
        init_bias(acc, pb + L*128, wm, lane);
        for (int kc = 0; kc < 4; kc++) {
            stage_A(As, w + L*16384, 128, kc*32, tid);
            __syncthreads();                       // As + (Bc writes) visible
            mfma_step_s(As, Bc, PSTR, kc*32, lane, wm, wn_, acc);
            __syncthreads();                       // done reading As
        }
        const float* ss = ps + L*128;
        const float* tt = pbb + L*128;
        if (L < 2) {
#pragma unroll
            for (int i = 0; i < 4; i++)
#pragma unroll
                for (int r = 0; r < 4; r++) {
                    int co = wm*64 + i*16 + quad*4 + r;
                    float s1 = ss[co], t1 = tt[co];
#pragma unroll
                    for (int j = 0; j < 4; j++) {
                        float v = relu(acc[i][j][r] * s1 + t1);
                        Bn[(wn_*64 + j*16 + l15)*PSTR + co] = f2bits(v);
                    }
                }
            u16* t = Bc; Bc = Bn; Bn = t;
        } else {
#pragma unroll
            for (int i = 0; i < 4; i++)
#pragma unroll
                for (int r = 0; r < 4; r++) {
                    int co = wm*64 + i*16 + quad*4 + r;
                    float s1 = ss[co], t1 = tt[co];
#pragma unroll
                    for (int j = 0; j < 4; j++) {
                        float v = relu(acc[i][j][r] * s1 + t1);
                        out[co*HW_ + pix0 + wn_*64 + j*16 + l15] = f2bits(v);
                    }
                }
        }
    }
}

// ---------------------------------------------------------------------------
// WeightNet: xyz fp32 -> bf16 [16,25,H2,W2] per batch.
// ---------------------------------------------------------------------------
__global__ __launch_bounds__(256)
void wn_kernel(const float* __restrict__ xyz0,
               const float* __restrict__ w1w, const float* __restrict__ w1b,
               const float* __restrict__ w2w, const float* __restrict__ w2b,
               const float* __restrict__ w3w, const float* __restrict__ w3b,
               const float* __restrict__ s1, const float* __restrict__ bb1,
               const float* __restrict__ s2, const float* __restrict__ bb2,
               const float* __restrict__ s3, const float* __restrict__ bb3,
               u16* __restrict__ out0)
{
    const float* xyz = xyz0 + (size_t)blockIdx.y*3*HW_;
    u16* out = out0 + (size_t)blockIdx.y*400*HW2_;
    int idx = blockIdx.x*256 + threadIdx.x;
    int j = idx & (W2_-1); int t = idx >> 9;
    int i = t & (H2_-1);   int k = t >> 5;
    int kh = k / 5, kw = k - kh*5;
    int yy = 2*i + kh - 2, xx = 2*j + kw - 2;
    bool inr = (yy >= 0 && yy < H_ && xx >= 0 && xx < W_);

    float g[3];
#pragma unroll
    for (int c = 0; c < 3; c++) {
        float ctr = xyz[c*HW_ + (2*i)*W_ + 2*j];
        float v = inr ? xyz[c*HW_ + yy*W_ + xx] : 0.f;
        g[c] = v - ctr;
    }
    float a1[8];
#pragma unroll
    for (int n = 0; n < 8; n++) {
        float v = w1b[n];
#pragma unroll
        for (int c = 0; c < 3; c++) v += w1w[n*3 + c] * g[c];
        a1[n] = relu(v * s1[n] + bb1[n]);
    }
    float a2[8];
#pragma unroll
    for (int n = 0; n < 8; n++) {
        float v = w2b[n];
#pragma unroll
        for (int m = 0; m < 8; m++) v += w2w[n*8 + m] * a1[m];
        a2[n] = relu(v * s2[n] + bb2[n]);
    }
#pragma unroll
    for (int n = 0; n < 16; n++) {
        float v = w3b[n];
#pragma unroll
        for (int m = 0; m < 8; m++) v += w3w[n*8 + m] * a2[m];
        v = relu(v * s3[n] + bb3[n]);
        out[(n*25 + k)*HW2_ + i*W2_ + j] = f2bits(v);
    }
}

// ---------------------------------------------------------------------------
// Fused ycompute + linear head, pipelined (R5 design on the R7-proven base):
//   y[px][c*16+n] = sum_k unf(h)[c][k][px] * wn[n][k][px]     (bf16, LDS only)
//   resB[co][px]  = relu(bn(lin_w @ y + lin_b))               (fp32 out)
// grid (32 i2 * 8 jt, B_), block 512.  16 chunks of 8 ch = K 128 each.
// Pipeline per chunk (2 barriers):
//   [issue fill(t+1)->regs | issue A(t) first half] ; y-compute slab[cur]->Bs
//   bar ; [A second half | ds_write fill(t+1)->slab[nxt]] overlapped with MFMA
//   bar.
// Fill latency (global loads) hides under the y-compute VALU phase — attacks
// the measured 33%-VALUBusy / 22%-occupancy serialization of the R7 form.
// LDS = 2*23.7 (slab dbuf) + 17.4 (Bs) = 64.8 KB -> 2 blocks/CU (VGPR-capped
// at 2 anyway).  Plain launch_bounds(512) — R3's min-arg spill lesson.
// Zero-fill note: xa is 8-aligned and W%8==0, so every 8-wide group is
// entirely in-bounds or entirely OOB (-> zeros); no partial groups exist.
// ---------------------------------------------------------------------------
__device__ __forceinline__ void yf_wr8(float* d, uint4 v)
{
    *(float2*)(d+0) = make_float2(bits2f((u16)(v.x & 0xffff)), bits2f((u16)(v.x >> 16)));
    *(float2*)(d+2) = make_float2(bits2f((u16)(v.y & 0xffff)), bits2f((u16)(v.y >> 16)));
    *(float2*)(d+4) = make_float2(bits2f((u16)(v.z & 0xffff)), bits2f((u16)(v.z >> 16)));
    *(float2*)(d+6) = make_float2(bits2f((u16)(v.w & 0xffff)), bits2f((u16)(v.w >> 16)));
}

__global__ __launch_bounds__(512)
void k_yfused(const u16* __restrict__ h0, const u16* __restrict__ wn0,
              const u16* __restrict__ w, const float* __restrict__ bias,
              const float* __restrict__ bns, const float* __restrict__ bnb,
              float* __restrict__ out0)
{
    __shared__ __align__(16) float slab[2][40*148];  // 2 x 23.7 KB
    __shared__ __align__(16) u16 Bs[64*PSTR];        // 17.4 KB (y sub-tile)
    const int tid = threadIdx.x;
    const int bx = blockIdx.x;
    const int j0 = (bx & 7) * 64;
    const int i2 = bx >> 3;
    const int b  = blockIdx.y;
    const u16* h  = h0  + (size_t)b*C_*HW_;
    const u16* wn = wn0 + (size_t)b*400*HW2_;
    float* out = out0 + (size_t)b*C_*HW2_;

    // phase-1 roles: n fast (16-way broadcast group), pxq = px-pair index
    const int n = tid & 15, pxq = tid >> 4;          // pxq 0..31
    // phase-2 roles
    const int lane = tid & 63, wave = tid >> 6;
    const int wm4 = wave & 3, wnp = wave >> 2;       // 4x32 co, 2x32 px
    const int quad = lane >> 4, l15 = lane & 15;

    // Fill slots: slot0 = e=tid (always), slot1 = e=tid+512 (tid<208).
    // Decode (cc, rr, g) once; per-chunk address = base + c0*HW_.
    const int e0 = tid;
    const int cc0 = e0/90, r0 = e0 - cc0*90, rr0 = r0/18, g0 = r0 - rr0*18;
    const int yy0 = 2*i2 + rr0 - 2, xa0 = 2*j0 - 8 + 8*g0;
    const bool ok0 = ((unsigned)yy0 < (unsigned)H_) && ((unsigned)xa0 <= (unsigned)(W_-8));
    const int src0 = cc0*HW_ + yy0*W_ + xa0;
    const int dst0 = (cc0*5 + rr0)*148 + 2 + 8*g0;

    const int e1 = tid + 512;
    const bool has1 = (e1 < 720);
    const int cc1 = e1/90, r1 = e1 - cc1*90, rr1 = r1/18, g1 = r1 - rr1*18;
    const int yy1 = 2*i2 + rr1 - 2, xa1 = 2*j0 - 8 + 8*g1;
    const bool ok1 = has1 && ((unsigned)yy1 < (unsigned)H_) && ((unsigned)xa1 <= (unsigned)(W_-8));
    const int src1 = cc1*HW_ + yy1*W_ + xa1;
    const int dst1 = (cc1*5 + rr1)*148 + 2 + 8*g1;

    // wn for this thread's (n, px-pair): 25 taps f32 in regs (50 VGPR)
    float wnreg[25][2];
    {
        const u16* wb = wn + (n*25)*HW2_ + i2*W2_ + j0 + pxq*2;
#pragma unroll
        for (int k = 0; k < 25; k++) {
            u32 t = *(const u32*)(wb + k*HW2_);
            wnreg[k][0] = bits2f((u16)(t & 0xffff));
            wnreg[k][1] = bits2f((u16)(t >> 16));
        }
    }

    // A-fragment lane base offsets into lin_w [128][2048]
    const int bA0 = (wm4*32 +  0 + l15)*2048 + quad*8;
    const int bA1 = (wm4*32 + 16 + l15)*2048 + quad*8;

    f32x4 acc[2][2];
#pragma unroll
    for (int i = 0; i < 2; i++)
#pragma unroll
        for (int r = 0; r < 4; r++) {
            float bv = bias[wm4*32 + i*16 + quad*4 + r];
            acc[i][0][r] = bv;
            acc[i][1][r] = bv;
        }

    // Prologue: fill chunk 0 into slab[0]
    {
        uint4 v0 = make_uint4(0u,0u,0u,0u), v1 = make_uint4(0u,0u,0u,0u);
        if (ok0) v0 = *(const uint4*)&h[src0];
        if (ok1) v1 = *(const uint4*)&h[src1];
        yf_wr8(&slab[0][dst0], v0);
        if (has1) yf_wr8(&slab[0][dst1], v1);
    }
    __syncthreads();

    for (int t = 0; t < 16; t++) {
        const int c0 = t*8;
        const float* scur = slab[t & 1];
        float* snxt = slab[(t & 1) ^ 1];

        // Issue next chunk's fill loads (held in regs; written after mid-bar)
        uint4 v0 = make_uint4(0u,0u,0u,0u), v1 = make_uint4(0u,0u,0u,0u);
        if (t < 15) {
            const int ch = (c0 + 8)*HW_;
            if (ok0) v0 = *(const uint4*)&h[src0 + ch];
            if (ok1) v1 = *(const uint4*)&h[src1 + ch];
        }
        // Issue first half of A-fragments (kc 0..1) — L2-resident lin_w
        bf16x8 afA[2][2];
#pragma unroll
        for (int kc = 0; kc < 2; kc++) {
            afA[0][kc] = *(const bf16x8*)&w[bA0 + c0*16 + kc*32];
            afA[1][kc] = *(const bf16x8*)&w[bA1 + c0*16 + kc*32];
        }

        // y-compute from scur -> Bs [px][cc*16+n]  (fill loads in flight)
#pragma unroll 2
        for (int cc = 0; cc < 8; cc++) {
            float yv0 = 0.f, yv1 = 0.f;
#pragma unroll
            for (int rr = 0; rr < 5; rr++) {
                const float* fr = &scur[(cc*5 + rr)*148 + 8 + 4*pxq];
                float4 A  = *(const float4*)fr;
                float4 Bv = *(const float4*)(fr + 4);
                yv0 += A.x*wnreg[rr*5+0][0] + A.y*wnreg[rr*5+1][0]
                     + A.z*wnreg[rr*5+2][0] + A.w*wnreg[rr*5+3][0]
                     + Bv.x*wnreg[rr*5+4][0];
                yv1 += A.z*wnreg[rr*5+0][1] + A.w*wnreg[rr*5+1][1]
                     + Bv.x*wnreg[rr*5+2][1] + Bv.y*wnreg[rr*5+3][1]
                     + Bv.z*wnreg[rr*5+4][1];
            }
            Bs[(2*pxq)  *PSTR + cc*16 + n] = f2bits(yv0);
            Bs[(2*pxq+1)*PSTR + cc*16 + n] = f2bits(yv1);
        }
        __syncthreads();                         // Bs ready; scur fully consumed

        // Second half of A-fragments (kc 2..3)
        bf16x8 afB[2][2];
#pragma unroll
        for (int kc = 0; kc < 2; kc++) {
            afB[0][kc] = *(const bf16x8*)&w[bA0 + c0*16 + (kc+2)*32];
            afB[1][kc] = *(const bf16x8*)&w[bA1 + c0*16 + (kc+2)*32];
        }
        // Write next chunk's slab (overlaps with MFMA below)
        if (t < 15) {
            yf_wr8(&snxt[dst0], v0);
            if (has1) yf_wr8(&snxt[dst1], v1);
        }
        // MFMA: A from regs, B from Bs
#pragma unroll
        for (int kc = 0; kc < 4; kc++) {
            bf16x8 b0 = *(const bf16x8*)&Bs[(wnp*32 +  0 + l15)*PSTR + kc*32 + quad*8];
            bf16x8 b1 = *(const bf16x8*)&Bs[(wnp*32 + 16 + l15)*PSTR + kc*32 + quad*8];
            bf16x8 a0 = (kc < 2) ? afA[0][kc] : afB[0][kc-2];
            bf16x8 a1 = (kc < 2) ? afA[1][kc] : afB[1][kc-2];
            acc[0][0] = __builtin_amdgcn_mfma_f32_16x16x32_bf16(a0, b0, acc[0][0], 0, 0, 0);
            acc[0][1] = __builtin_amdgcn_mfma_f32_16x16x32_bf16(a0, b1, acc[0][1], 0, 0, 0);
            acc[1][0] = __builtin_amdgcn_mfma_f32_16x16x32_bf16(a1, b0, acc[1][0], 0, 0, 0);
            acc[1][1] = __builtin_amdgcn_mfma_f32_16x16x32_bf16(a1, b1, acc[1][1], 0, 0, 0);
        }
        __syncthreads();                         // Bs free; snxt visible
    }
    // epilogue: bn + relu -> fp32 resB
#pragma unroll
    for (int i = 0; i < 2; i++)
#pragma unroll
        for (int r = 0; r < 4; r++) {
            int co = wm4*32 + i*16 + quad*4 + r;
            float ss = bns[co], tt = bnb[co];
#pragma unroll
            for (int j = 0; j < 2; j++) {
                float v = relu(acc[i][j][r] * ss + tt);
                out[co*HW2_ + i2*W2_ + j0 + wnp*32 + j*16 + l15] = v;
            }
        }
}

// ---------------------------------------------------------------------------
// Weight transform: fp32 -> bf16 g_wts (k-contiguous layouts).
// ---------------------------------------------------------------------------
__global__ __launch_bounds__(256)
void k_wtrans(const float* __restrict__ c2w, const float* __restrict__ c3w,
              const float* __restrict__ c4w, const float* __restrict__ c5w,
              const float* __restrict__ c1w, const float* __restrict__ pw,
              const float* __restrict__ linw)
{
    int i = blockIdx.x*256 + threadIdx.x;
    if (i >= WTS_TOT) return;
    float v;
    if (i < OFF_C3) {
        int p = i / 8192, rem = i - p*8192;
        int co = rem >> 6, ci = rem & 63;
        v = c2w[(co*64 + ci)*9 + p];
    } else if (i < OFF_C4) {
        int t = i - OFF_C3;
        int p = t / 16384, rem = t - p*16384;
        int co = rem >> 7, ci = rem & 127;
        v = c3w[(co*128 + ci)*9 + p];
    } else if (i < OFF_C5) {
        int t = i - OFF_C4;
        int p = t / 16384, rem = t - p*16384;
        int co = rem >> 7, ci = rem & 127;
        v = c4w[(co*128 + ci)*4 + p];
    } else if (i < OFF_C1)  v = c5w[i - OFF_C5];
    else if (i < OFF_PW)    v = c1w[i - OFF_C1];
    else if (i < OFF_LIN)   v = pw[i - OFF_PW];
    else                    v = linw[i - OFF_LIN];
    g_wts[i] = f2bits(v);
}

// ---------------------------------------------------------------------------
extern "C" void kernel_launch(void* const* d_in, const int* in_sizes, int n_in,
                              void* d_out, int out_size, void* d_ws, size_t ws_size,
                              hipStream_t stream)
{
    const float* x     = (const float*)d_in[0];
    const float* xyz   = (const float*)d_in[1];
    const float* c1_w  = (const float*)d_in[2];
    const float* c1_b  = (const float*)d_in[3];
    const float* c2_w  = (const float*)d_in[4];
    const float* c2_b  = (const float*)d_in[5];
    const float* c3_w  = (const float*)d_in[6];
    const float* c3_b  = (const float*)d_in[7];
    const float* c4_w  = (const float*)d_in[8];
    const float* c4_b  = (const float*)d_in[9];
    const float* c5_w  = (const float*)d_in[10];
    const float* c5_b  = (const float*)d_in[11];
    const float* rbn_s = (const float*)d_in[12];
    const float* rbn_b = (const float*)d_in[13];
    const float* p_w   = (const float*)d_in[14];
    const float* p_b   = (const float*)d_in[15];
    const float* pbn_s = (const float*)d_in[16];
    const float* pbn_b = (const float*)d_in[17];
    const float* lin_w = (const float*)d_in[18];
    const float* lin_b = (const float*)d_in[19];
    const float* w1_w  = (const float*)d_in[20];
    const float* w1_b  = (const float*)d_in[21];
    const float* w2_w  = (const float*)d_in[22];
    const float* w2_b  = (const float*)d_in[23];
    const float* w3_w  = (const float*)d_in[24];
    const float* w3_b  = (const float*)d_in[25];
    const float* wbn1_s = (const float*)d_in[26];
    const float* wbn1_b = (const float*)d_in[27];
    const float* wbn2_s = (const float*)d_in[28];
    const float* wbn2_b = (const float*)d_in[29];
    const float* wbn3_s = (const float*)d_in[30];
    const float* wbn3_b = (const float*)d_in[31];

    float* outB = (float*)d_out;                     // [2,128,32,512] fp32
    float* outA = outB + (size_t)B_*C_*HW2_;         // [2,128,64,1024] fp32

    u16 *wts, *b1, *b2, *b3, *xb;
    { void* p; hipGetSymbolAddress(&p, HIP_SYMBOL(g_wts)); wts = (u16*)p; }
    { void* p; hipGetSymbolAddress(&p, HIP_SYMBOL(g_b1));  b1  = (u16*)p; }
    { void* p; hipGetSymbolAddress(&p, HIP_SYMBOL(g_b2));  b2  = (u16*)p; }
    { void* p; hipGetSymbolAddress(&p, HIP_SYMBOL(g_b3));  b3  = (u16*)p; }
    { void* p; hipGetSymbolAddress(&p, HIP_SYMBOL(g_xb));  xb  = (u16*)p; }

    dim3 blk(256);

    k_wtrans<<<dim3((WTS_TOT + 255)/256), blk, 0, stream>>>(c2_w, c3_w, c4_w, c5_w,
                                                            c1_w, p_w, lin_w);
    k_xtrans<<<dim3(512, B_), blk, 0, stream>>>(x, xb);
    k_conv<64,3,1,1><<<dim3(512, B_), blk, 0, stream>>>(xb, wts+OFF_C2, c2_b,
                                                        rbn_s, rbn_b, b1);
    k_conv<128,3,2,2><<<dim3(512, B_), blk, 0, stream>>>(b1, wts+OFF_C3, c3_b,
                                                         rbn_s+128, rbn_b+128, b2);
    k_conv<128,2,2,1><<<dim3(512, B_), blk, 0, stream>>>(b2, wts+OFF_C4, c4_b,
                                                         rbn_s+256, rbn_b+256, b3);
    k_resA<<<dim3(512, B_), blk, 0, stream>>>(xb, b1, b2, b3, wts+OFF_C1, c1_b,
                                              wts+OFF_C5, c5_b, rbn_s+384, rbn_b+384, outA);
    k_pw3<<<dim3(512, B_), blk, 0, stream>>>(outA, wts+OFF_PW, p_b, pbn_s, pbn_b, b1);
    wn_kernel<<<dim3(1600, B_), blk, 0, stream>>>(xyz, w1_w, w1_b, w2_w, w2_b, w3_w, w3_b,
                                                  wbn1_s, wbn1_b, wbn2_s, wbn2_b,
                                                  wbn3_s, wbn3_b, b2);
    k_yfused<<<dim3(256, B_), dim3(512), 0, stream>>>(b1, b2, wts+OFF_LIN, lin_b,
                                                      pbn_s+384, pbn_b+384, outB);
}